// Round 2
// baseline (1113.662 us; speedup 1.0000x reference)
//
#include <hip/hip_runtime.h>
#include <hip/hip_bf16.h>
#include <math.h>

// B=2048, C=128, H=4, L=2, P=106, D=32, N_PRED=217088
// Structure exploited:
//  - pred nodes receive exactly 1 edge -> alpha==1 -> pred path collapses
//  - news-side softmax invariant to per-(b,h) constants -> c0 bias dropped,
//    p_rel*scale folded into score weights
//  - scores: Us = xn @ Wcomb (Wcomb = Wq_news @ WkT_fold, prescaled), coalesced GEMM
//  - agg: Ys (per-head alpha-weighted xp-row sums) @ Wv_full (block-diag, zero-padded)
//  - xp rows recomputed on the fly from U/V low-rank decomposition
//  - att output is a constant fill (fused single pass)

__device__ __forceinline__ float wsum(float v){
#pragma unroll
  for (int o=32;o;o>>=1) v += __shfl_xor(v,o);
  return v;
}
__device__ __forceinline__ float gelu_f(float x){
  return 0.5f*x*(1.f+erff(x*0.70710678118654752f));
}
__device__ __forceinline__ float elu_f(float x){ return x>0.f?x:expm1f(x); }

template<int K, int N, bool GELU_IN, int BLK>
__global__ __launch_bounds__(BLK) void gemm_bias(const float* __restrict__ X, int ldx,
    const float* __restrict__ W, int ldw, const float* __restrict__ bias,
    float* __restrict__ Y, int ldy, int rows)
{
  constexpr int RPB = 8;
  __shared__ float xs[RPB][K];
  const int r0 = blockIdx.x * RPB;
  const int tid = threadIdx.x;
  constexpr int V4 = RPB*(K/4);
  for (int i = tid; i < V4; i += BLK){
    int r = i/(K/4); int kk = (i%(K/4))*4;
    float4 v = make_float4(0.f,0.f,0.f,0.f);
    if (r0+r < rows) v = *reinterpret_cast<const float4*>(X + (long)(r0+r)*ldx + kk);
    if (GELU_IN){ v.x=gelu_f(v.x); v.y=gelu_f(v.y); v.z=gelu_f(v.z); v.w=gelu_f(v.w); }
    *reinterpret_cast<float4*>(&xs[r][kk]) = v;
  }
  __syncthreads();
  constexpr int GROUPS = BLK/N;
  constexpr int RT = RPB/GROUPS;
  const int j = tid % N;
  const int rg = tid / N;
  float acc[RT];
#pragma unroll
  for (int r=0;r<RT;r++) acc[r] = bias ? bias[j] : 0.f;
#pragma unroll 4
  for (int k=0;k<K;k++){
    float w = W[(long)k*ldw + j];
#pragma unroll
    for (int r=0;r<RT;r++) acc[r] += xs[rg*RT+r][k]*w;
  }
#pragma unroll
  for (int r=0;r<RT;r++){
    int rr = r0 + rg*RT + r;
    if (rr < rows) Y[(long)rr*ldy + j] = acc[r];
  }
}

// MODE 0: out = elu(LN(A;g,b))
// MODE 1: out = LN(A;g,b) + R
// MODE 2: out = elu(LN(sn*A + (1-sn)*Bx + R; g,b)), sn = sigmoid(skip[0])
template<int MODE>
__global__ __launch_bounds__(256) void ln_kernel(const float* __restrict__ A,
    const float* __restrict__ Bx, const float* __restrict__ R,
    const float* __restrict__ g, const float* __restrict__ beta,
    const float* __restrict__ skip, float* __restrict__ out, int rows)
{
  int row = blockIdx.x*4 + (threadIdx.x>>6);
  if (row >= rows) return;
  int lane = threadIdx.x & 63;
  int c0=lane, c1=lane+64;
  float t0, t1;
  if (MODE==2){
    float sn = 1.f/(1.f+expf(-skip[0])); float osn = 1.f - sn;
    t0 = sn*A[(long)row*128+c0] + osn*Bx[(long)row*128+c0] + R[(long)row*128+c0];
    t1 = sn*A[(long)row*128+c1] + osn*Bx[(long)row*128+c1] + R[(long)row*128+c1];
  } else {
    t0 = A[(long)row*128+c0]; t1 = A[(long)row*128+c1];
  }
  float m = wsum(t0+t1)*(1.f/128.f);
  float d0=t0-m, d1=t1-m;
  float var = wsum(d0*d0+d1*d1)*(1.f/128.f);
  float inv = rsqrtf(var+1e-5f);
  float y0 = d0*inv*g[c0]+beta[c0];
  float y1 = d1*inv*g[c1]+beta[c1];
  if (MODE==0 || MODE==2){ y0=elu_f(y0); y1=elu_f(y1); }
  if (MODE==1){ y0 += R[(long)row*128+c0]; y1 += R[(long)row*128+c1]; }
  out[(long)row*128+c0]=y0; out[(long)row*128+c1]=y1;
}

__global__ __launch_bounds__(256) void center_stats(float* __restrict__ M,
    float* __restrict__ snorm, int rows)
{
  int row = blockIdx.x*4 + (threadIdx.x>>6);
  if (row >= rows) return;
  int lane = threadIdx.x & 63;
  float t0=M[(long)row*128+lane], t1=M[(long)row*128+lane+64];
  float m = wsum(t0+t1)*(1.f/128.f);
  t0-=m; t1-=m;
  float ss = wsum(t0*t0+t1*t1);
  M[(long)row*128+lane]=t0; M[(long)row*128+lane+64]=t1;
  if (lane==0) snorm[row]=ss;
}

// Weight folds. Tasks by blockIdx.x:
//  0..7  : WkTc[l][h][e][cc] = prel*scale * sum_d kqv_pw_k[cc][h*32+d]*a_rel[l][1][h][d][e]
//  8..15 : Wv_full[l][h*128+cc][j] = (j in h range)? sum_d' kqv_pw_v[cc][h*32+d']*m_rel[l][1][h][d'][j&31] : 0
// 16..19 : Wnv[c][h*32+d] = sum_d' kqv_nw_v[c][h*32+d']*m_rel[0][0][h][d'][d]
//  20    : bv_full[l][j], bnv[j]
__global__ __launch_bounds__(256) void prep_fold(
    const float* __restrict__ kqv_pw, const float* __restrict__ kqv_pb,
    const float* __restrict__ kqv_nw, const float* __restrict__ kqv_nb,
    const float* __restrict__ a_rel, const float* __restrict__ m_rel,
    const float* __restrict__ p_rel,
    float* __restrict__ WkTc, float* __restrict__ Wv_full,
    float* __restrict__ bv_full, float* __restrict__ Wnv, float* __restrict__ bnv)
{
  const int task = blockIdx.x, tid = threadIdx.x;
  __shared__ float rl[1024];
  if (task < 8){
    int l = task>>2, h = task&3;
    for (int i=tid;i<1024;i+=256) rl[i]=a_rel[((l*2+1)*4+h)*1024 + i];
    __syncthreads();
    float ps = p_rel[(l*2+1)*4 + h] * 0.17677669529663687f;
    for (int idx=tid; idx<4096; idx+=256){
      int e = idx>>7, cc = idx&127;
      float acc=0.f;
#pragma unroll
      for (int d=0;d<32;d++) acc += kqv_pw[(long)l*49152 + cc*384 + h*32 + d]*rl[d*32+e];
      WkTc[((l*4+h)*32 + e)*128 + cc] = acc*ps;
    }
  } else if (task < 16){
    int l=(task-8)>>2, h=(task-8)&3;
    for (int i=tid;i<1024;i+=256) rl[i]=m_rel[((l*2+1)*4+h)*1024 + i];
    __syncthreads();
    for (int idx=tid; idx<16384; idx+=256){
      int cc = idx>>7, j = idx&127;
      int jh = j>>5, d = j&31;
      float acc = 0.f;
      if (jh==h){
#pragma unroll
        for(int dp=0;dp<32;dp++) acc += kqv_pw[(long)l*49152 + cc*384 + 256 + h*32 + dp]*rl[dp*32+d];
      }
      Wv_full[((long)l*512 + h*128 + cc)*128 + j] = acc;
    }
  } else if (task < 20){
    int h = task-16;
    for (int i=tid;i<1024;i+=256) rl[i]=m_rel[h*1024 + i];
    __syncthreads();
    for (int idx=tid; idx<4096; idx+=256){
      int c = idx>>5, d = idx&31;
      float acc=0.f;
#pragma unroll
      for (int dp=0;dp<32;dp++) acc += kqv_nw[c*384 + 256 + h*32 + dp]*rl[dp*32+d];
      Wnv[c*128 + h*32 + d]=acc;
    }
  } else {
    {
      int l = tid>>7, j = tid&127, h=j>>5, d=j&31;
      float acc=0.f;
#pragma unroll
      for (int dp=0;dp<32;dp++) acc += kqv_pb[l*384 + 256 + h*32+dp]*m_rel[((l*2+1)*4+h)*1024 + dp*32 + d];
      bv_full[l*128 + j]=acc;
    }
    if (tid < 128){
      int j=tid, h=j>>5, d=j&31;
      float acc=0.f;
#pragma unroll
      for (int dp=0;dp<32;dp++) acc += kqv_nb[256 + h*32+dp]*m_rel[h*1024 + dp*32 + d];
      bnv[j]=acc;
    }
  }
}

// Wcomb[l][c][h*128+cc] = sum_e kqv_nw_q[c][h*32+e]*WkTc[l][h][e][cc]; bcomb likewise from kqv_nb_q
__global__ __launch_bounds__(256) void prep_comb(
    const float* __restrict__ kqv_nw, const float* __restrict__ kqv_nb,
    const float* __restrict__ WkTc,
    float* __restrict__ Wcomb, float* __restrict__ bcomb)
{
  int l = blockIdx.x>>3, jq = blockIdx.x&7;
  int h = jq>>1;
  int cc0 = (jq&1)*64;
  __shared__ float wk[32][64];
  int tid=threadIdx.x;
  for (int i=tid;i<2048;i+=256){ int e=i>>6, c=i&63; wk[e][c]=WkTc[((l*4+h)*32+e)*128 + cc0 + c]; }
  __syncthreads();
  for (int idx=tid; idx<8192; idx+=256){
    int c = idx>>6, jl = idx&63;
    float acc=0.f;
#pragma unroll
    for (int e=0;e<32;e++) acc += kqv_nw[(long)l*49152 + c*384 + 128 + h*32 + e]*wk[e][jl];
    Wcomb[(long)l*65536 + c*512 + h*128 + cc0 + jl] = acc;
  }
  if (tid<64){
    float acc=0.f;
#pragma unroll
    for (int e=0;e<32;e++) acc += kqv_nb[l*384 + 128 + h*32 + e]*wk[e][tid];
    bcomb[l*512 + h*128 + cc0 + tid] = acc;
  }
}

template<int LAYER>
__global__ __launch_bounds__(256) void attn2(
    const float* __restrict__ A1, const float* __restrict__ Up,
    const float* __restrict__ sa1,
    const float* __restrict__ B1v, const float* __restrict__ Vn,
    const float* __restrict__ sb1,
    const float* __restrict__ Us,        // 2048x512 prescaled score weights
    const float* __restrict__ lin_pg, const float* __restrict__ lin_pbeta,
    const float* __restrict__ W0row,
    const float* __restrict__ ln_pg0, const float* __restrict__ ln_pbeta0,
    const float* __restrict__ skip_p,
    float* __restrict__ Ys)              // 2048x512 (h-major)
{
  __shared__ float tile[106][128];
  __shared__ float us[512];
  __shared__ float Bv[128], Vv[128], gA[128], bA[128];
  __shared__ float W0s[128], g0[128], b0[128];
  __shared__ float ss[4][128];
  const int b = blockIdx.x, tid = threadIdx.x, lane = tid&63, wid = tid>>6;
  for (int i=tid;i<512;i+=256) us[i] = Us[(long)b*512+i];
  for (int i=tid;i<128;i+=256){
    Bv[i]=B1v[(long)b*128+i]; Vv[i]=Vn[(long)b*128+i];
    gA[i]=lin_pg[i]; bA[i]=lin_pbeta[i];
    if (LAYER==1){ W0s[i]=W0row[(long)b*128+i]; g0[i]=ln_pg0[i]; b0[i]=ln_pbeta0[i]; }
  }
  const float sb = sb1[b];
  float sp0=0.f, omsp=0.f;
  if (LAYER==1){ sp0 = 1.f/(1.f+expf(-skip_p[0])); omsp = 1.f - sp0; }
  __syncthreads();
  for (int p = wid; p < 106; p += 4){
    int c1 = lane, c2 = lane+64;
    float a1v = A1[p*128+c1], a2v = A1[p*128+c2];
    float u1 = Up[p*128+c1],  u2 = Up[p*128+c2];
    float bv1 = Bv[c1], bv2 = Bv[c2];
    float dot = wsum(a1v*bv1 + a2v*bv2);
    float var = (sa1[p] + 2.f*dot + sb) * (1.f/128.f);
    float inv = rsqrtf(var + 1e-5f);
    float x1 = (a1v+bv1)*inv*gA[c1] + bA[c1] + u1 + Vv[c1];
    float x2 = (a2v+bv2)*inv*gA[c2] + bA[c2] + u2 + Vv[c2];
    float r1, r2;
    if (LAYER==1){
      float t1 = sp0*W0s[c1] + omsp*x1 + u1 + Vv[c1];
      float t2 = sp0*W0s[c2] + omsp*x2 + u2 + Vv[c2];
      float m = wsum(t1+t2)*(1.f/128.f);
      float d1=t1-m, d2=t2-m;
      float v2s = wsum(d1*d1+d2*d2)*(1.f/128.f);
      float inv2 = rsqrtf(v2s+1e-5f);
      float y1 = d1*inv2*g0[c1]+b0[c1];
      float y2 = d2*inv2*g0[c2]+b0[c2];
      r1 = elu_f(y1); r2 = elu_f(y2);
    } else { r1 = x1; r2 = x2; }
    tile[p][c1]=r1; tile[p][c2]=r2;
    float s0 = r1*us[0*128+c1] + r2*us[0*128+c2];
    float s1 = r1*us[1*128+c1] + r2*us[1*128+c2];
    float s2 = r1*us[2*128+c1] + r2*us[2*128+c2];
    float s3 = r1*us[3*128+c1] + r2*us[3*128+c2];
    s0=wsum(s0); s1=wsum(s1); s2=wsum(s2); s3=wsum(s3);
    if (lane==0){ ss[0][p]=s0; ss[1][p]=s1; ss[2][p]=s2; ss[3][p]=s3; }
  }
  __syncthreads();
  { // softmax: wave wid = head wid over 106 entries
    int h = wid;
    int p1 = lane, p2 = lane+64;
    float v1 = (p1<106)? ss[h][p1] : -1e30f;
    float v2 = (p2<106)? ss[h][p2] : -1e30f;
    float mx = fmaxf(v1,v2);
#pragma unroll
    for (int o=32;o;o>>=1) mx = fmaxf(mx,__shfl_xor(mx,o));
    float e1 = (p1<106)? expf(v1-mx):0.f;
    float e2 = (p2<106)? expf(v2-mx):0.f;
    float den = wsum(e1+e2);
    float rinv = 1.f/den;
    if (p1<106) ss[h][p1]=e1*rinv;
    if (p2<106) ss[h][p2]=e2*rinv;
  }
  __syncthreads();
  for (int idx=tid; idx<512; idx+=256){
    int h = idx>>7, cc = idx&127;
    float acc=0.f;
#pragma unroll 2
    for (int p=0;p<106;p++) acc += ss[h][p]*tile[p][cc];
    Ys[(long)b*512 + idx] = acc;
  }
}

__global__ void logits_kernel(const float* __restrict__ xn, const float* __restrict__ cls_w,
                              const float* __restrict__ cls_b, float* __restrict__ out)
{
  int row = blockIdx.x*4 + (threadIdx.x>>6);
  int lane = threadIdx.x&63;
  const float* x = xn + (long)row*128;
  float a0=0.f,a1=0.f;
#pragma unroll
  for (int i=0;i<2;i++){
    int c = lane + i*64;
    float xv = x[c];
    a0 += xv*cls_w[c*2];
    a1 += xv*cls_w[c*2+1];
  }
  a0 = wsum(a0); a1 = wsum(a1);
  if (lane==0){ out[row*2]=a0+cls_b[0]; out[row*2+1]=a1+cls_b[1]; }
}

// att[b][i][j][h]: value = 1/e0 on (i==0, j>=1) else 1/107; one float4 per (i,j)
__global__ void fill_att_all(float4* __restrict__ att4, unsigned int n4){
  unsigned int i = blockIdx.x*256u + threadIdx.x;
  unsigned int stride = gridDim.x*256u;
  const float v1 = 1.f/107.f, v2 = 1.f/217088.f;
  for (; i<n4; i+=stride){
    unsigned int local = i % 11449u;
    float v = (local>=1u && local<107u) ? v2 : v1;
    att4[i] = make_float4(v,v,v,v);
  }
}

extern "C" void kernel_launch(void* const* d_in, const int* in_sizes, int n_in,
                              void* d_out, int out_size, void* d_ws, size_t ws_size,
                              hipStream_t stream) {
  const float* news_emb = (const float*)d_in[0];
  const float* base_embs= (const float*)d_in[1];
  const float* ctx_w  = (const float*)d_in[2];
  const float* ctx_b  = (const float*)d_in[3];
  const float* proj_w = (const float*)d_in[4];
  const float* proj_b = (const float*)d_in[5];
  const float* fus_w  = (const float*)d_in[6];
  const float* fus_b  = (const float*)d_in[7];
  const float* enc_w  = (const float*)d_in[8];
  const float* enc_b  = (const float*)d_in[9];
  const float* enc_g  = (const float*)d_in[10];
  const float* enc_beta=(const float*)d_in[11];
  const float* lin_nw = (const float*)d_in[12];
  const float* lin_nb = (const float*)d_in[13];
  const float* lin_ng = (const float*)d_in[14];
  const float* lin_nbeta=(const float*)d_in[15];
  const float* kqv_nw = (const float*)d_in[16];
  const float* kqv_nb = (const float*)d_in[17];
  const float* out_nw = (const float*)d_in[18];
  const float* out_nb = (const float*)d_in[19];
  const float* skip_n = (const float*)d_in[20];
  const float* ln_ng  = (const float*)d_in[21];
  const float* ln_nbeta=(const float*)d_in[22];
  const float* lin_pw = (const float*)d_in[23];
  const float* lin_pb = (const float*)d_in[24];
  const float* lin_pg = (const float*)d_in[25];
  const float* lin_pbeta=(const float*)d_in[26];
  const float* kqv_pw = (const float*)d_in[27];
  const float* kqv_pb = (const float*)d_in[28];
  const float* out_pw = (const float*)d_in[29];
  const float* out_pb = (const float*)d_in[30];
  const float* skip_p = (const float*)d_in[31];
  const float* ln_pg  = (const float*)d_in[32];
  const float* ln_pbeta=(const float*)d_in[33];
  const float* a_rel  = (const float*)d_in[34];
  const float* m_rel  = (const float*)d_in[35];
  const float* p_rel  = (const float*)d_in[36];
  const float* cls_w  = (const float*)d_in[37];
  const float* cls_b  = (const float*)d_in[38];
  (void)in_sizes; (void)n_in; (void)out_size; (void)d_ws; (void)ws_size;

  float* out = (float*)d_out;
  float* S = out + 4096;            // att region as scratch; constant-filled last
  float* news_ctx = S + 0;
  float* Vb       = S + 262144;
  float* B1v      = S + 524288;
  float* sb1      = S + 786432;
  float* encpre   = S + 788480;
  float* xn_enc   = S + 1050624;
  float* linn     = S + 1312768;
  float* xn1      = S + 1574912;
  float* Us       = S + 1837056;    // 2048*512
  float* Ys       = S + 2885632;    // 2048*512
  float* agg      = S + 3934208;
  float* onb      = S + 4196352;
  float* v0b      = S + 4458496;
  float* W0row    = S + 4720640;
  float* xnA      = S + 4982784;
  float* xnB      = S + 5244928;
  float* pred_base= S + 5507072;
  float* Ub       = S + 5520640;
  float* A1       = S + 5534208;
  float* sa1      = S + 5547776;
  float* WkTc     = S + 5547904;    // 2*4*32*128
  float* Wv_full  = S + 5580672;    // 2*512*128
  float* bv_full  = S + 5711744;    // 2*128
  float* Wnv      = S + 5712000;    // 128*128
  float* bnv      = S + 5728384;    // 128
  float* Wcomb    = S + 5728512;    // 2*128*512
  float* bcomb    = S + 5859584;    // 2*512

  dim3 blk(256), blk5(512);
  // Weight prep (depends only on inputs)
  prep_fold<<<21,blk,0,stream>>>(kqv_pw,kqv_pb,kqv_nw,kqv_nb,a_rel,m_rel,p_rel,
                                 WkTc,Wv_full,bv_full,Wnv,bnv);
  prep_comb<<<16,blk,0,stream>>>(kqv_nw,kqv_nb,WkTc,Wcomb,bcomb);
  // Input projections (K=1024, 8 waves/block)
  gemm_bias<1024,128,false,512><<<256,blk5,0,stream>>>(news_emb,1024,ctx_w,128,ctx_b,news_ctx,128,2048);
  gemm_bias<1024,128,false,512><<<14, blk5,0,stream>>>(base_embs,1024,proj_w,128,proj_b,pred_base,128,106);
  gemm_bias<1024,128,false,512><<<256,blk5,0,stream>>>(news_emb,1024,enc_w,128,enc_b,encpre,128,2048);
  ln_kernel<0><<<512,blk,0,stream>>>(encpre,nullptr,nullptr,enc_g,enc_beta,nullptr,xn_enc,2048);
  // fusion low-rank parts: xp0[b,p] = Ub[p] + Vb[b]
  gemm_bias<128,128,false,256><<<14, blk,0,stream>>>(pred_base,128,fus_w,128,fus_b,Ub,128,106);
  gemm_bias<128,128,false,256><<<256,blk,0,stream>>>(news_ctx,128,fus_w+16384,128,nullptr,Vb,128,2048);
  // lin_p folded low-rank + center/norms
  gemm_bias<128,128,false,256><<<14, blk,0,stream>>>(Ub,128,lin_pw,128,nullptr,A1,128,106);
  gemm_bias<128,128,false,256><<<256,blk,0,stream>>>(Vb,128,lin_pw,128,lin_pb,B1v,128,2048);
  center_stats<<<27, blk,0,stream>>>(A1,sa1,106);
  center_stats<<<512,blk,0,stream>>>(B1v,sb1,2048);
  // news lin
  gemm_bias<128,128,false,256><<<256,blk,0,stream>>>(xn_enc,128,lin_nw,128,lin_nb,linn,128,2048);
  ln_kernel<1><<<512,blk,0,stream>>>(linn,nullptr,xn_enc,lin_ng,lin_nbeta,nullptr,xn1,2048);
  // ---- layer 0 ----
  gemm_bias<128,256,false,256><<<256,blk,0,stream>>>(xn1,128,Wcomb,512,bcomb,Us,512,2048);
  gemm_bias<128,256,false,256><<<256,blk,0,stream>>>(xn1,128,Wcomb+256,512,bcomb+256,Us+256,512,2048);
  attn2<0><<<2048,blk,0,stream>>>(A1,Ub,sa1,B1v,Vb,sb1,Us,lin_pg,lin_pbeta,
                                  nullptr,nullptr,nullptr,nullptr,Ys);
  gemm_bias<512,128,false,256><<<256,blk,0,stream>>>(Ys,512,Wv_full,128,bv_full,agg,128,2048);
  gemm_bias<128,128,true ,256><<<256,blk,0,stream>>>(agg,128,out_nw,128,out_nb,onb,128,2048);
  ln_kernel<2><<<512,blk,0,stream>>>(onb,xn1,xn_enc,ln_ng,ln_nbeta,skip_n,xnA,2048);
  // pred-side row update for layer-1 xp: W0row = gelu(xn1@Wnv+bnv)@out_pw0+out_pb0
  gemm_bias<128,128,false,256><<<256,blk,0,stream>>>(xn1,128,Wnv,128,bnv,v0b,128,2048);
  gemm_bias<128,128,true ,256><<<256,blk,0,stream>>>(v0b,128,out_pw,128,out_pb,W0row,128,2048);
  // ---- layer 1 ----
  gemm_bias<128,256,false,256><<<256,blk,0,stream>>>(xnA,128,Wcomb+65536,512,bcomb+512,Us,512,2048);
  gemm_bias<128,256,false,256><<<256,blk,0,stream>>>(xnA,128,Wcomb+65536+256,512,bcomb+512+256,Us+256,512,2048);
  attn2<1><<<2048,blk,0,stream>>>(A1,Ub,sa1,B1v,Vb,sb1,Us,lin_pg,lin_pbeta,
                                  W0row,ln_pg,ln_pbeta,skip_p,Ys);
  gemm_bias<512,128,false,256><<<256,blk,0,stream>>>(Ys,512,Wv_full+65536,128,bv_full+128,agg,128,2048);
  gemm_bias<128,128,true ,256><<<256,blk,0,stream>>>(agg,128,out_nw+16384,128,out_nb+128,onb,128,2048);
  ln_kernel<2><<<512,blk,0,stream>>>(onb,xnA,xnA,ln_ng+128,ln_nbeta+128,skip_n+1,xnB,2048);
  // outputs
  logits_kernel<<<512,blk,0,stream>>>(xnB,cls_w,cls_b,out);
  fill_att_all<<<4096,blk,0,stream>>>(reinterpret_cast<float4*>(S), 23447552u);
}

// Round 3
// 859.206 us; speedup vs baseline: 1.2962x; 1.2962x over previous
//
#include <hip/hip_runtime.h>
#include <math.h>

// B=2048, C=128, H=4, L=2, P=106, D=32
// 4 launches: PREP0 (folds + pred chain), PREP1 (news K=1024 pass),
// MEGA (whole per-b pipeline, 1 block per b), FILL (constant att output).

#define DEVFN __device__ __forceinline__

DEVFN float wsum(float v){
#pragma unroll
  for (int o=32;o;o>>=1) v += __shfl_xor(v,o);
  return v;
}
DEVFN float gelu_f(float x){ return 0.5f*x*(1.f+erff(x*0.70710678118654752f)); }
DEVFN float elu_f(float x){ return x>0.f?x:expm1f(x); }
DEVFN float sigm(float x){ return 1.f/(1.f+expf(-x)); }

// out[j] = sum_k xs[k]*W[k*128+j] + bias[j]; 256 thr = 128 j x 2 k-halves
DEVFN void gemv128(const float* __restrict__ W, const float* __restrict__ bias,
    const float* xs, float* outs, float* red, int tid){
  int j = tid&127, kg = tid>>7;
  const float* Wp = W + (long)(kg*64)*128 + j;
  const float* xp = xs + kg*64;
  float acc=0.f;
#pragma unroll 8
  for (int k=0;k<64;k++) acc += xp[k]*Wp[(long)k*128];
  red[tid]=acc;
  __syncthreads();
  if (tid<128) outs[tid] = red[tid]+red[tid+128]+bias[tid];
  __syncthreads();
}

// outs[0:512] = xs[0:128] @ W[128][512] + bias
DEVFN void gemv512(const float* __restrict__ W, const float* __restrict__ bias,
    const float* xs, float* outs, int tid){
  float a0=bias[tid], a1=bias[256+tid];
#pragma unroll 4
  for (int k=0;k<128;k++){
    float xv=xs[k];
    a0 += xv*W[(long)k*512+tid];
    a1 += xv*W[(long)k*512+256+tid];
  }
  outs[tid]=a0; outs[256+tid]=a1;
  __syncthreads();
}

// agg[h*32+d] = sum_cc Ys[h*128+cc]*WvC[(h*128+cc)*32+d] + bv[h*32+d]
DEVFN void aggv(const float* __restrict__ WvC, const float* __restrict__ bv,
   const float* Ysr, float* outs, float* red, int tid){
  int d=tid&31, h=(tid>>5)&3, cg=tid>>7;
  const float* Wp = WvC + (long)((h*128 + cg*64)*32) + d;
  const float* yp = Ysr + h*128 + cg*64;
  float acc=0.f;
#pragma unroll 8
  for (int i=0;i<64;i++) acc += yp[i]*Wp[i*32];
  red[tid]=acc;
  __syncthreads();
  if (tid<128) outs[tid]=red[tid]+red[tid+128]+bv[tid];
  __syncthreads();
}

// out = elu(LN(sn*A + (1-sn)*Bx + R; g,be))
DEVFN void rowmode2(const float* A, const float* Bx, const float* R,
  const float* __restrict__ g, const float* __restrict__ be, float skipval,
  float* outr, int lane, int wid){
  if (wid==0){
    float sn = sigm(skipval), os = 1.f-sn;
    float t0 = sn*A[lane] + os*Bx[lane] + R[lane];
    float t1 = sn*A[lane+64] + os*Bx[lane+64] + R[lane+64];
    float m = wsum(t0+t1)*(1.f/128.f);
    float d0=t0-m, d1=t1-m;
    float var=wsum(d0*d0+d1*d1)*(1.f/128.f);
    float inv=rsqrtf(var+1e-5f);
    outr[lane]=elu_f(d0*inv*g[lane]+be[lane]);
    outr[lane+64]=elu_f(d1*inv*g[lane+64]+be[lane+64]);
  }
  __syncthreads();
}

template<int LAYER>
DEVFN void attn_stage(int tid, int lane, int wid,
    const float* __restrict__ A1, const float* __restrict__ Ub,
    const float* __restrict__ sa1, float sb,
    const float* __restrict__ ling, const float* __restrict__ linb,
    const float* __restrict__ g0, const float* __restrict__ b0,
    float sp0, float omsp,
    float (*tile)[128], float* us, float* ss, float* Ys,
    const float* Bv, const float* Vv, const float* W0s)
{
  for (int p = wid; p < 106; p += 4){
    int c1 = lane, c2 = lane+64;
    float r1, r2;
    if (LAYER==0){
      float a1v = A1[p*128+c1], a2v = A1[p*128+c2];
      float u1 = Ub[p*128+c1], u2 = Ub[p*128+c2];
      float bv1 = Bv[c1], bv2 = Bv[c2];
      float dot = wsum(a1v*bv1 + a2v*bv2);
      float var = (sa1[p] + 2.f*dot + sb)*(1.f/128.f);
      float inv = rsqrtf(var + 1e-5f);
      r1 = (a1v+bv1)*inv*ling[c1] + linb[c1] + u1 + Vv[c1];
      r2 = (a2v+bv2)*inv*ling[c2] + linb[c2] + u2 + Vv[c2];
    } else {
      float xv1 = tile[p][c1], xv2 = tile[p][c2];
      float u1 = Ub[p*128+c1], u2 = Ub[p*128+c2];
      float t1 = sp0*W0s[c1] + omsp*xv1 + u1 + Vv[c1];
      float t2 = sp0*W0s[c2] + omsp*xv2 + u2 + Vv[c2];
      float m = wsum(t1+t2)*(1.f/128.f);
      float d1=t1-m, d2=t2-m;
      float v2s = wsum(d1*d1+d2*d2)*(1.f/128.f);
      float inv2 = rsqrtf(v2s+1e-5f);
      r1 = elu_f(d1*inv2*g0[c1]+b0[c1]);
      r2 = elu_f(d2*inv2*g0[c2]+b0[c2]);
    }
    tile[p][c1]=r1; tile[p][c2]=r2;
    float s0 = r1*us[c1]     + r2*us[c2];
    float s1 = r1*us[128+c1] + r2*us[128+c2];
    float s2 = r1*us[256+c1] + r2*us[256+c2];
    float s3 = r1*us[384+c1] + r2*us[384+c2];
    s0=wsum(s0); s1=wsum(s1); s2=wsum(s2); s3=wsum(s3);
    if (lane==0){ ss[0*128+p]=s0; ss[1*128+p]=s1; ss[2*128+p]=s2; ss[3*128+p]=s3; }
  }
  __syncthreads();
  {
    int h = wid;
    int p1=lane, p2=lane+64;
    float v1 = (p1<106)? ss[h*128+p1] : -1e30f;
    float v2 = (p2<106)? ss[h*128+p2] : -1e30f;
    float mx = fmaxf(v1,v2);
#pragma unroll
    for (int o=32;o;o>>=1) mx = fmaxf(mx,__shfl_xor(mx,o));
    float e1 = (p1<106)? expf(v1-mx):0.f;
    float e2 = (p2<106)? expf(v2-mx):0.f;
    float den = wsum(e1+e2);
    float rinv = 1.f/den;
    if (p1<106) ss[h*128+p1]=e1*rinv;
    if (p2<106) ss[h*128+p2]=e2*rinv;
  }
  __syncthreads();
  for (int idx=tid; idx<512; idx+=256){
    int h = idx>>7, cc = idx&127;
    float acc=0.f;
#pragma unroll 2
    for (int p=0;p<106;p++) acc += ss[h*128+p]*tile[p][cc];
    Ys[idx]=acc;          // Ys aliases us; all us reads complete before here
  }
  __syncthreads();
}

__global__ __launch_bounds__(256,2) void mega(
  const float* __restrict__ xn_enc_g, const float* __restrict__ Vv_g,
  const float* __restrict__ B1v_g, const float* __restrict__ sb1_g,
  const float* __restrict__ Ub, const float* __restrict__ A1, const float* __restrict__ sa1,
  const float* __restrict__ Wcomb, const float* __restrict__ bcomb,
  const float* __restrict__ WvC, const float* __restrict__ bv2,
  const float* __restrict__ Wnv, const float* __restrict__ bnv,
  const float* __restrict__ lin_nw, const float* __restrict__ lin_nb,
  const float* __restrict__ lin_ng, const float* __restrict__ lin_nbeta,
  const float* __restrict__ lin_pg, const float* __restrict__ lin_pbeta,
  const float* __restrict__ ln_pg, const float* __restrict__ ln_pbeta,
  const float* __restrict__ out_nw, const float* __restrict__ out_nb,
  const float* __restrict__ out_pw, const float* __restrict__ out_pb,
  const float* __restrict__ skip_n, const float* __restrict__ skip_p,
  const float* __restrict__ ln_ng, const float* __restrict__ ln_nbeta,
  const float* __restrict__ cls_w, const float* __restrict__ cls_b,
  float* __restrict__ out)
{
  __shared__ float tile[106][128];
  __shared__ float us[512];
  __shared__ float ss[512];
  __shared__ float xe[128], x1[128], xA[128], rowa[128], rowb[128];
  __shared__ float Bv[128], Vvs[128], W0s[128];
  __shared__ float red[256];
  float* Ys = us;
  const int b = blockIdx.x, tid=threadIdx.x, lane=tid&63, wid=tid>>6;
  if (tid<128){
    xe[tid]=xn_enc_g[(long)b*128+tid];
    Bv[tid]=B1v_g[(long)b*128+tid];
    Vvs[tid]=Vv_g[(long)b*128+tid];
  }
  __syncthreads();
  // linn = xe@lin_nw + lin_nb
  gemv128(lin_nw, lin_nb, xe, rowa, red, tid);
  // x1 = LN(linn; lin_ng, lin_nbeta) + xe
  if (wid==0){
    float t0=rowa[lane], t1=rowa[lane+64];
    float m=wsum(t0+t1)*(1.f/128.f);
    float d0=t0-m,d1=t1-m;
    float var=wsum(d0*d0+d1*d1)*(1.f/128.f);
    float inv=rsqrtf(var+1e-5f);
    x1[lane]   =d0*inv*lin_ng[lane]   +lin_nbeta[lane]   +xe[lane];
    x1[lane+64]=d1*inv*lin_ng[lane+64]+lin_nbeta[lane+64]+xe[lane+64];
  }
  __syncthreads();
  // layer 0
  gemv512(Wcomb, bcomb, x1, us, tid);
  attn_stage<0>(tid,lane,wid,A1,Ub,sa1,sb1_g[b],lin_pg,lin_pbeta,ln_pg,ln_pbeta,
                0.f,0.f,tile,us,ss,Ys,Bv,Vvs,W0s);
  aggv(WvC, bv2, Ys, rowa, red, tid);
  if (tid<128) rowb[tid]=gelu_f(rowa[tid]);
  __syncthreads();
  gemv128(out_nw, out_nb, rowb, rowa, red, tid);
  rowmode2(rowa, x1, xe, ln_ng, ln_nbeta, skip_n[0], xA, lane, wid);
  // pred-side layer-0 output row (same for all p of this b)
  gemv128(Wnv, bnv, x1, rowa, red, tid);
  if (tid<128) rowb[tid]=gelu_f(rowa[tid]);
  __syncthreads();
  gemv128(out_pw, out_pb, rowb, W0s, red, tid);
  // layer 1
  gemv512(Wcomb+65536, bcomb+512, xA, us, tid);
  float sp0 = sigm(skip_p[0]);
  attn_stage<1>(tid,lane,wid,A1,Ub,sa1,sb1_g[b],lin_pg,lin_pbeta,ln_pg,ln_pbeta,
                sp0,1.f-sp0,tile,us,ss,Ys,Bv,Vvs,W0s);
  aggv(WvC+16384, bv2+128, Ys, rowa, red, tid);
  if (tid<128) rowb[tid]=gelu_f(rowa[tid]);
  __syncthreads();
  gemv128(out_nw+16384, out_nb+128, rowb, rowa, red, tid);
  rowmode2(rowa, xA, xA, ln_ng+128, ln_nbeta+128, skip_n[1], rowb, lane, wid);
  // logits
  if (wid==0){
    float xv0=rowb[lane], xv1=rowb[lane+64];
    float a0=xv0*cls_w[lane*2]   + xv1*cls_w[(lane+64)*2];
    float a1=xv0*cls_w[lane*2+1] + xv1*cls_w[(lane+64)*2+1];
    a0=wsum(a0); a1=wsum(a1);
    if (lane==0){ out[b*2]=a0+cls_b[0]; out[b*2+1]=a1+cls_b[1]; }
  }
}

__global__ __launch_bounds__(256) void prep0(
  const float* __restrict__ ctx_w, const float* __restrict__ ctx_b,
  const float* __restrict__ enc_w,
  const float* __restrict__ proj_w, const float* __restrict__ proj_b,
  const float* __restrict__ base_embs,
  const float* __restrict__ fus_w, const float* __restrict__ fus_b,
  const float* __restrict__ lin_pw, const float* __restrict__ lin_pb,
  const float* __restrict__ kqv_nw, const float* __restrict__ kqv_nb,
  const float* __restrict__ kqv_pw, const float* __restrict__ kqv_pb,
  const float* __restrict__ a_rel, const float* __restrict__ m_rel,
  const float* __restrict__ p_rel,
  float* __restrict__ Wcomb, float* __restrict__ bcomb,
  float* __restrict__ WvC, float* __restrict__ bv2,
  float* __restrict__ Wnv, float* __restrict__ bnv,
  float* __restrict__ Wbig, float* __restrict__ bVb, float* __restrict__ bB1,
  float* __restrict__ Ub, float* __restrict__ A1, float* __restrict__ sa1)
{
  const int blk=blockIdx.x, tid=threadIdx.x, lane=tid&63, wid=tid>>6;
  __shared__ float sh[2048];
  __shared__ float row1[128], row2[128], row3[128];
  __shared__ float red[256];
  if (blk < 16){
    // Wcomb/bcomb for (l, h, cc-half): scores fully folded, prescaled
    int l=blk>>3, jq=blk&7, h=jq>>1, cc0=(jq&1)*64;
    float* wk = sh; // [32 e][64 cl]
    float ps = p_rel[(l*2+1)*4+h]*0.17677669529663687f;
    for (int idx=tid; idx<2048; idx+=256){
      int e=idx>>6, cl=idx&63;
      float acc=0.f;
#pragma unroll
      for (int d=0;d<32;d++)
        acc += kqv_pw[(long)l*49152 + (cc0+cl)*384 + h*32 + d]
             * a_rel[((l*2+1)*4+h)*1024 + d*32 + e];
      wk[e*64+cl]=acc*ps;
    }
    __syncthreads();
    for (int idx=tid; idx<8192; idx+=256){
      int c=idx>>6, jl=idx&63;
      float acc=0.f;
#pragma unroll
      for (int e=0;e<32;e++) acc += kqv_nw[(long)l*49152 + c*384 + 128 + h*32 + e]*wk[e*64+jl];
      Wcomb[(long)l*65536 + c*512 + h*128 + cc0 + jl]=acc;
    }
    if (tid<64){
      float acc=0.f;
#pragma unroll
      for (int e=0;e<32;e++) acc += kqv_nb[l*384 + 128 + h*32 + e]*wk[e*64+tid];
      bcomb[l*512 + h*128 + cc0 + tid]=acc;
    }
  } else if (blk < 24){
    // WvC[l][h*128+cc][d] = sum_dp Wv_p[cc][h*32+dp]*m_rel[l,1,h,dp,d]
    int t=blk-16, l=t>>2, h=t&3;
    float* rl = sh;
    for (int i=tid;i<1024;i+=256) rl[i]=m_rel[((l*2+1)*4+h)*1024+i];
    __syncthreads();
    for (int idx=tid; idx<4096; idx+=256){
      int cc=idx>>5, d=idx&31;
      float acc=0.f;
#pragma unroll
      for (int dp=0;dp<32;dp++) acc += kqv_pw[(long)l*49152 + cc*384 + 256 + h*32 + dp]*rl[dp*32+d];
      WvC[l*16384 + (h*128+cc)*32 + d]=acc;
    }
  } else if (blk==24){
    {
      int l=tid>>7, j=tid&127, h=(j>>5)&3, d=j&31;
      float acc=0.f;
#pragma unroll
      for (int dp=0;dp<32;dp++) acc += kqv_pb[l*384+256+h*32+dp]*m_rel[((l*2+1)*4+h)*1024+dp*32+d];
      bv2[l*128+j]=acc;
    }
    if (tid<128){
      int j=tid, h=j>>5, d=j&31;
      float acc=0.f;
#pragma unroll
      for (int dp=0;dp<32;dp++) acc += kqv_nb[256+h*32+dp]*m_rel[h*1024+dp*32+d];
      bnv[j]=acc;
    }
  } else if (blk < 29){
    // Wnv (layer0, edge news->pred)
    int h=blk-25;
    float* rl=sh;
    for (int i=tid;i<1024;i+=256) rl[i]=m_rel[h*1024+i];
    __syncthreads();
    for (int idx=tid; idx<4096; idx+=256){
      int c=idx>>5, d=idx&31;
      float acc=0.f;
#pragma unroll
      for (int dp=0;dp<32;dp++) acc += kqv_nw[c*384+256+h*32+dp]*rl[dp*32+d];
      Wnv[c*128 + h*32 + d]=acc;
    }
  } else if (blk==29){
    // bVb = ctx_b@fusW2 ; bB1 = bVb@lin_pw + lin_pb
    int j=tid&127, kg=tid>>7;
    float acc=0.f;
#pragma unroll 4
    for (int i=0;i<64;i++) acc += ctx_b[kg*64+i]*fus_w[(128+kg*64+i)*128+j];
    red[tid]=acc; __syncthreads();
    if (tid<128){ float v=red[tid]+red[tid+128]; bVb[tid]=v; row1[tid]=v; }
    __syncthreads();
    acc=0.f;
#pragma unroll 4
    for (int i=0;i<64;i++) acc += row1[kg*64+i]*lin_pw[(kg*64+i)*128+j];
    red[tid]=acc; __syncthreads();
    if (tid<128) bB1[tid]=red[tid]+red[tid+128]+lin_pb[tid];
  } else if (blk < 94){
    // Wbig[k][0:128]=enc_w row; [128:256]=ctx_w@fusW2; [256:384]=that@lin_pw
    int k0=(blk-30)*16;
    int j=tid&127, kg=tid>>7;
    for (int rr=0; rr<16; rr++){
      int k=k0+rr;
      if (tid<128){ row1[tid]=ctx_w[(long)k*128+tid]; Wbig[(long)k*384+tid]=enc_w[(long)k*128+tid]; }
      __syncthreads();
      float acc=0.f;
#pragma unroll 4
      for (int i=0;i<64;i++) acc += row1[kg*64+i]*fus_w[(128+kg*64+i)*128+j];
      red[tid]=acc; __syncthreads();
      if (tid<128){ float v=red[tid]+red[tid+128]; Wbig[(long)k*384+128+tid]=v; row2[tid]=v; }
      __syncthreads();
      acc=0.f;
#pragma unroll 4
      for (int i=0;i<64;i++) acc += row2[kg*64+i]*lin_pw[(kg*64+i)*128+j];
      red[tid]=acc; __syncthreads();
      if (tid<128) Wbig[(long)k*384+256+tid]=red[tid]+red[tid+128];
      __syncthreads();
    }
  } else {
    // pred chain: base_embs -> pred_base -> Ub -> A1 (centered) + sa1
    int p0=(blk-94)*8;
    float* xs1=sh;
    int j=tid&127, kg=tid>>7;
    for (int rr=0; rr<8; rr++){
      int p=p0+rr;
      if (p>=106) break;
      for (int i=tid;i<1024;i+=256) xs1[i]=base_embs[(long)p*1024+i];
      __syncthreads();
      float acc=0.f;
#pragma unroll 4
      for (int k=0;k<512;k++) acc += xs1[kg*512+k]*proj_w[(long)(kg*512+k)*128+j];
      red[tid]=acc; __syncthreads();
      if (tid<128) row1[tid]=red[tid]+red[tid+128]+proj_b[tid];
      __syncthreads();
      acc=0.f;
#pragma unroll 4
      for (int i=0;i<64;i++) acc += row1[kg*64+i]*fus_w[(long)(kg*64+i)*128+j];
      red[tid]=acc; __syncthreads();
      if (tid<128){ float v=red[tid]+red[tid+128]+fus_b[tid]; row2[tid]=v; Ub[(long)p*128+tid]=v; }
      __syncthreads();
      acc=0.f;
#pragma unroll 4
      for (int i=0;i<64;i++) acc += row2[kg*64+i]*lin_pw[(long)(kg*64+i)*128+j];
      red[tid]=acc; __syncthreads();
      if (tid<128) row3[tid]=red[tid]+red[tid+128];
      __syncthreads();
      if (wid==0){
        float t0=row3[lane], t1=row3[lane+64];
        float m=wsum(t0+t1)*(1.f/128.f);
        t0-=m; t1-=m;
        float ssq=wsum(t0*t0+t1*t1);
        A1[(long)p*128+lane]=t0; A1[(long)p*128+lane+64]=t1;
        if (lane==0) sa1[p]=ssq;
      }
      __syncthreads();
    }
  }
}

__global__ __launch_bounds__(256) void prep1(
  const float* __restrict__ news_emb, const float* __restrict__ Wbig,
  const float* __restrict__ enc_b, const float* __restrict__ enc_g, const float* __restrict__ enc_beta,
  const float* __restrict__ bVb, const float* __restrict__ bB1,
  float* __restrict__ xn_enc, float* __restrict__ Vv, float* __restrict__ B1v, float* __restrict__ sb1)
{
  __shared__ __align__(16) float xs[4][1024];
  __shared__ float red2[1024];
  __shared__ float rows[4][128];
  const int r0=blockIdx.x*4, tid=threadIdx.x, lane=tid&63, wid=tid>>6;
  for (int r=0;r<4;r++){
    float4 v = *reinterpret_cast<const float4*>(news_emb + (long)(r0+r)*1024 + tid*4);
    *reinterpret_cast<float4*>(&xs[r][tid*4]) = v;
  }
  __syncthreads();
  const int j=tid&127, kg=tid>>7;
  for (int chunk=0; chunk<3; chunk++){
    const float* Wp = Wbig + (long)(kg*512)*384 + chunk*128 + j;
    float a0=0.f,a1=0.f,a2=0.f,a3=0.f;
#pragma unroll 2
    for (int k=0;k<512;k++){
      float w = Wp[(long)k*384];
      a0+=xs[0][kg*512+k]*w; a1+=xs[1][kg*512+k]*w;
      a2+=xs[2][kg*512+k]*w; a3+=xs[3][kg*512+k]*w;
    }
    red2[(kg*4+0)*128+j]=a0; red2[(kg*4+1)*128+j]=a1;
    red2[(kg*4+2)*128+j]=a2; red2[(kg*4+3)*128+j]=a3;
    __syncthreads();
    if (kg==0){
#pragma unroll
      for (int r=0;r<4;r++) rows[r][j]=red2[r*128+j]+red2[(4+r)*128+j];
    }
    __syncthreads();
    if (chunk==0){
      float t0=rows[wid][lane]+enc_b[lane], t1=rows[wid][lane+64]+enc_b[lane+64];
      float m=wsum(t0+t1)*(1.f/128.f);
      float d0=t0-m,d1=t1-m;
      float var=wsum(d0*d0+d1*d1)*(1.f/128.f);
      float inv=rsqrtf(var+1e-5f);
      xn_enc[(long)(r0+wid)*128+lane]   =elu_f(d0*inv*enc_g[lane]   +enc_beta[lane]);
      xn_enc[(long)(r0+wid)*128+lane+64]=elu_f(d1*inv*enc_g[lane+64]+enc_beta[lane+64]);
    } else if (chunk==1){
      for (int idx=tid; idx<512; idx+=256){
        int r=idx>>7, jj=idx&127;
        Vv[(long)(r0+r)*128+jj]=rows[r][jj]+bVb[jj];
      }
    } else {
      float t0=rows[wid][lane]+bB1[lane], t1=rows[wid][lane+64]+bB1[lane+64];
      float m=wsum(t0+t1)*(1.f/128.f);
      t0-=m; t1-=m;
      float ssq=wsum(t0*t0+t1*t1);
      B1v[(long)(r0+wid)*128+lane]=t0; B1v[(long)(r0+wid)*128+lane+64]=t1;
      if (lane==0) sb1[r0+wid]=ssq;
    }
    __syncthreads();
  }
}

// att[b][i][j][h] = 1/107 everywhere except [b][0][1..106][:] = 1/217088
__global__ void fill_att_all(float4* __restrict__ att4, unsigned int n4){
  unsigned int i = blockIdx.x*256u + threadIdx.x;
  unsigned int stride = gridDim.x*256u;
  const float v1 = 1.f/107.f, v2 = 1.f/217088.f;
  for (; i<n4; i+=stride){
    unsigned int local = i % 11449u;
    float v = (local>=1u && local<107u) ? v2 : v1;
    att4[i] = make_float4(v,v,v,v);
  }
}

extern "C" void kernel_launch(void* const* d_in, const int* in_sizes, int n_in,
                              void* d_out, int out_size, void* d_ws, size_t ws_size,
                              hipStream_t stream) {
  const float* news_emb = (const float*)d_in[0];
  const float* base_embs= (const float*)d_in[1];
  const float* ctx_w  = (const float*)d_in[2];
  const float* ctx_b  = (const float*)d_in[3];
  const float* proj_w = (const float*)d_in[4];
  const float* proj_b = (const float*)d_in[5];
  const float* fus_w  = (const float*)d_in[6];
  const float* fus_b  = (const float*)d_in[7];
  const float* enc_w  = (const float*)d_in[8];
  const float* enc_b  = (const float*)d_in[9];
  const float* enc_g  = (const float*)d_in[10];
  const float* enc_beta=(const float*)d_in[11];
  const float* lin_nw = (const float*)d_in[12];
  const float* lin_nb = (const float*)d_in[13];
  const float* lin_ng = (const float*)d_in[14];
  const float* lin_nbeta=(const float*)d_in[15];
  const float* kqv_nw = (const float*)d_in[16];
  const float* kqv_nb = (const float*)d_in[17];
  const float* out_nw = (const float*)d_in[18];
  const float* out_nb = (const float*)d_in[19];
  const float* skip_n = (const float*)d_in[20];
  const float* ln_ng  = (const float*)d_in[21];
  const float* ln_nbeta=(const float*)d_in[22];
  const float* lin_pw = (const float*)d_in[23];
  const float* lin_pb = (const float*)d_in[24];
  const float* lin_pg = (const float*)d_in[25];
  const float* lin_pbeta=(const float*)d_in[26];
  const float* kqv_pw = (const float*)d_in[27];
  const float* kqv_pb = (const float*)d_in[28];
  const float* out_pw = (const float*)d_in[29];
  const float* out_pb = (const float*)d_in[30];
  const float* skip_p = (const float*)d_in[31];
  const float* ln_pg  = (const float*)d_in[32];
  const float* ln_pbeta=(const float*)d_in[33];
  const float* a_rel  = (const float*)d_in[34];
  const float* m_rel  = (const float*)d_in[35];
  const float* p_rel  = (const float*)d_in[36];
  const float* cls_w  = (const float*)d_in[37];
  const float* cls_b  = (const float*)d_in[38];
  (void)in_sizes; (void)n_in; (void)out_size; (void)d_ws; (void)ws_size;

  float* out = (float*)d_out;
  float* S = out + 4096;            // att region as scratch; constant-filled last
  float* xn_enc = S + 0;            // 2048*128
  float* Vv     = S + 262144;       // 2048*128
  float* B1v    = S + 524288;       // 2048*128
  float* sb1    = S + 786432;       // 2048
  float* Ub     = S + 788480;       // 106*128
  float* A1     = S + 802048;       // 106*128
  float* sa1    = S + 815616;       // 106 (pad to 128)
  float* WvC    = S + 815744;       // 2*512*32
  float* bv2    = S + 848512;       // 2*128
  float* Wnv    = S + 848768;       // 128*128
  float* bnv    = S + 865152;       // 128
  float* Wcomb  = S + 865280;       // 2*128*512
  float* bcomb  = S + 996352;       // 2*512
  float* Wbig   = S + 997376;       // 1024*384
  float* bVb    = S + 1390592;      // 128
  float* bB1    = S + 1390720;      // 128

  dim3 blk(256);
  prep0<<<108,blk,0,stream>>>(ctx_w,ctx_b,enc_w,proj_w,proj_b,base_embs,
      fus_w,fus_b,lin_pw,lin_pb,kqv_nw,kqv_nb,kqv_pw,kqv_pb,a_rel,m_rel,p_rel,
      Wcomb,bcomb,WvC,bv2,Wnv,bnv,Wbig,bVb,bB1,Ub,A1,sa1);
  prep1<<<512,blk,0,stream>>>(news_emb,Wbig,enc_b,enc_g,enc_beta,bVb,bB1,
      xn_enc,Vv,B1v,sb1);
  mega<<<2048,blk,0,stream>>>(xn_enc,Vv,B1v,sb1,Ub,A1,sa1,Wcomb,bcomb,WvC,bv2,Wnv,bnv,
      lin_nw,lin_nb,lin_ng,lin_nbeta,lin_pg,lin_pbeta,ln_pg,ln_pbeta,
      out_nw,out_nb,out_pw,out_pb,skip_n,skip_p,ln_ng,ln_nbeta,cls_w,cls_b,out);
  fill_att_all<<<4096,blk,0,stream>>>(reinterpret_cast<float4*>(S), 23447552u);
}

// Round 4
// 587.792 us; speedup vs baseline: 1.8947x; 1.4618x over previous
//
#include <hip/hip_runtime.h>
#include <math.h>

// B=2048, C=128, H=4, L=2, P=106, D=32
// 4 launches: PREP0 (folds + pred chain), PREP1 (news K=1024 pass),
// MEGA (whole per-b pipeline, streaming 2-pass attention, ~17.5KB LDS),
// FILL (constant att output).

#define DEVFN __device__ __forceinline__

DEVFN float wsum(float v){
#pragma unroll
  for (int o=32;o;o>>=1) v += __shfl_xor(v,o);
  return v;
}
DEVFN float gelu_f(float x){ return 0.5f*x*(1.f+erff(x*0.70710678118654752f)); }
DEVFN float elu_f(float x){ return x>0.f?x:expm1f(x); }
DEVFN float sigm(float x){ return 1.f/(1.f+expf(-x)); }

// out[j] = sum_k xs[k]*W[k*128+j] + bias[j]; 256 thr = 128 j x 2 k-halves
DEVFN void gemv128(const float* __restrict__ W, const float* __restrict__ bias,
    const float* xs, float* outs, float* red, int tid){
  int j = tid&127, kg = tid>>7;
  const float* Wp = W + (long)(kg*64)*128 + j;
  const float* xp = xs + kg*64;
  float acc=0.f;
#pragma unroll 8
  for (int k=0;k<64;k++) acc += xp[k]*Wp[(long)k*128];
  red[tid]=acc;
  __syncthreads();
  if (tid<128) outs[tid] = red[tid]+red[tid+128]+bias[tid];
  __syncthreads();
}

// outs[0:512] = xs[0:128] @ W[128][512] + bias
DEVFN void gemv512(const float* __restrict__ W, const float* __restrict__ bias,
    const float* xs, float* outs, int tid){
  float a0=bias[tid], a1=bias[256+tid];
#pragma unroll 4
  for (int k=0;k<128;k++){
    float xv=xs[k];
    a0 += xv*W[(long)k*512+tid];
    a1 += xv*W[(long)k*512+256+tid];
  }
  outs[tid]=a0; outs[256+tid]=a1;
  __syncthreads();
}

// agg[h*32+d] = sum_cc Ys[h*128+cc]*WvC[(h*128+cc)*32+d] + bv[h*32+d]
DEVFN void aggv(const float* __restrict__ WvC, const float* __restrict__ bv,
   const float* Ysr, float* outs, float* red, int tid){
  int d=tid&31, h=(tid>>5)&3, cg=tid>>7;
  const float* Wp = WvC + (long)((h*128 + cg*64)*32) + d;
  const float* yp = Ysr + h*128 + cg*64;
  float acc=0.f;
#pragma unroll 8
  for (int i=0;i<64;i++) acc += yp[i]*Wp[i*32];
  red[tid]=acc;
  __syncthreads();
  if (tid<128) outs[tid]=red[tid]+red[tid+128]+bv[tid];
  __syncthreads();
}

// out = elu(LN(sn*A + (1-sn)*Bx + R; g,be))
DEVFN void rowmode2(const float* A, const float* Bx, const float* R,
  const float* __restrict__ g, const float* __restrict__ be, float skipval,
  float* outr, int lane, int wid){
  if (wid==0){
    float sn = sigm(skipval), os = 1.f-sn;
    float t0 = sn*A[lane] + os*Bx[lane] + R[lane];
    float t1 = sn*A[lane+64] + os*Bx[lane+64] + R[lane+64];
    float m = wsum(t0+t1)*(1.f/128.f);
    float d0=t0-m, d1=t1-m;
    float var=wsum(d0*d0+d1*d1)*(1.f/128.f);
    float inv=rsqrtf(var+1e-5f);
    outr[lane]=elu_f(d0*inv*g[lane]+be[lane]);
    outr[lane+64]=elu_f(d1*inv*g[lane+64]+be[lane+64]);
  }
  __syncthreads();
}

DEVFN void softmax106(float* ss, int lane, int wid){
  int h = wid;
  int p1=lane, p2=lane+64;
  float v1 = (p1<106)? ss[h*128+p1] : -1e30f;
  float v2 = (p2<106)? ss[h*128+p2] : -1e30f;
  float mx = fmaxf(v1,v2);
#pragma unroll
  for (int o=32;o;o>>=1) mx = fmaxf(mx,__shfl_xor(mx,o));
  float e1 = (p1<106)? expf(v1-mx):0.f;
  float e2 = (p2<106)? expf(v2-mx):0.f;
  float den = wsum(e1+e2);
  float rinv = 1.f/den;
  if (p1<106) ss[h*128+p1]=e1*rinv;
  if (p2<106) ss[h*128+p2]=e2*rinv;
}

__global__ __launch_bounds__(256,5) void mega(
  const float* __restrict__ xn_enc_g, const float* __restrict__ Vv_g,
  const float* __restrict__ B1v_g, const float* __restrict__ sb1_g,
  const float* __restrict__ Ub, const float* __restrict__ A1, const float* __restrict__ sa1,
  const float* __restrict__ Wcomb, const float* __restrict__ bcomb,
  const float* __restrict__ WvC, const float* __restrict__ bv2,
  const float* __restrict__ Wnv, const float* __restrict__ bnv,
  const float* __restrict__ lin_nw, const float* __restrict__ lin_nb,
  const float* __restrict__ lin_ng, const float* __restrict__ lin_nbeta,
  const float* __restrict__ lin_pg, const float* __restrict__ lin_pbeta,
  const float* __restrict__ ln_pg, const float* __restrict__ ln_pbeta,
  const float* __restrict__ out_nw, const float* __restrict__ out_nb,
  const float* __restrict__ out_pw, const float* __restrict__ out_pb,
  const float* __restrict__ skip_n, const float* __restrict__ skip_p,
  const float* __restrict__ ln_ng, const float* __restrict__ ln_nbeta,
  const float* __restrict__ cls_w, const float* __restrict__ cls_b,
  float* __restrict__ out)
{
  __shared__ float us[512];
  __shared__ float ss[512];
  __shared__ float red2[4][512];
  __shared__ float xe[128], x1[128], xA[128], rowa[128], rowb[128];
  __shared__ float Bv[128], Vvs[128], W0s[128];
  __shared__ float inv0[112], m1s[112], i1s[112];
  float* red = red2[0];
  const int b = blockIdx.x, tid=threadIdx.x, lane=tid&63, wid=tid>>6;
  if (tid<128){
    xe[tid]=xn_enc_g[(long)b*128+tid];
    Bv[tid]=B1v_g[(long)b*128+tid];
    Vvs[tid]=Vv_g[(long)b*128+tid];
  }
  __syncthreads();
  // linn = xe@lin_nw + lin_nb ; x1 = LN + xe
  gemv128(lin_nw, lin_nb, xe, rowa, red, tid);
  if (wid==0){
    float t0=rowa[lane], t1=rowa[lane+64];
    float m=wsum(t0+t1)*(1.f/128.f);
    float d0=t0-m,d1=t1-m;
    float var=wsum(d0*d0+d1*d1)*(1.f/128.f);
    float inv=rsqrtf(var+1e-5f);
    x1[lane]   =d0*inv*lin_ng[lane]   +lin_nbeta[lane]   +xe[lane];
    x1[lane+64]=d1*inv*lin_ng[lane+64]+lin_nbeta[lane+64]+xe[lane+64];
  }
  __syncthreads();
  const float sb = sb1_g[b];
  const float2 bv = ((const float2*)Bv)[lane];
  const float2 V2 = ((const float2*)Vvs)[lane];
  const float2 gA2 = ((const float2*)lin_pg)[lane];
  const float2 bA2 = ((const float2*)lin_pbeta)[lane];
  // ======== layer 0 ========
  gemv512(Wcomb, bcomb, x1, us, tid);
  // pass A: scores + cache inv0[p]
  for (int p=wid; p<106; p+=4){
    const float2 a = ((const float2*)(A1+p*128))[lane];
    const float2 u = ((const float2*)(Ub+p*128))[lane];
    float dot = wsum(a.x*bv.x + a.y*bv.y);
    float inv = rsqrtf((sa1[p]+2.f*dot+sb)*(1.f/128.f) + 1e-5f);
    if (lane==0) inv0[p]=inv;
    float rx = (a.x+bv.x)*inv*gA2.x + bA2.x + u.x + V2.x;
    float ry = (a.y+bv.y)*inv*gA2.y + bA2.y + u.y + V2.y;
    const float2 u0=((const float2*)us)[lane], u1=((const float2*)us)[64+lane];
    const float2 u2=((const float2*)us)[128+lane], u3=((const float2*)us)[192+lane];
    float s0=wsum(rx*u0.x+ry*u0.y);
    float s1=wsum(rx*u1.x+ry*u1.y);
    float s2=wsum(rx*u2.x+ry*u2.y);
    float s3=wsum(rx*u3.x+ry*u3.y);
    if (lane==0){ ss[p]=s0; ss[128+p]=s1; ss[256+p]=s2; ss[384+p]=s3; }
  }
  __syncthreads();
  softmax106(ss, lane, wid);
  __syncthreads();
  // pass B: recompute x rows, accumulate Ys
  {
    float2 ya0=make_float2(0.f,0.f), ya1=ya0, ya2=ya0, ya3=ya0;
    for (int p=wid; p<106; p+=4){
      const float2 a = ((const float2*)(A1+p*128))[lane];
      const float2 u = ((const float2*)(Ub+p*128))[lane];
      float inv = inv0[p];
      float rx = (a.x+bv.x)*inv*gA2.x + bA2.x + u.x + V2.x;
      float ry = (a.y+bv.y)*inv*gA2.y + bA2.y + u.y + V2.y;
      float al0=ss[p], al1=ss[128+p], al2=ss[256+p], al3=ss[384+p];
      ya0.x+=al0*rx; ya0.y+=al0*ry; ya1.x+=al1*rx; ya1.y+=al1*ry;
      ya2.x+=al2*rx; ya2.y+=al2*ry; ya3.x+=al3*rx; ya3.y+=al3*ry;
    }
    float2* rw = (float2*)red2[wid];
    rw[lane]=ya0; rw[64+lane]=ya1; rw[128+lane]=ya2; rw[192+lane]=ya3;
  }
  __syncthreads();
  for (int idx=tid; idx<512; idx+=256)
    us[idx]=red2[0][idx]+red2[1][idx]+red2[2][idx]+red2[3][idx];
  __syncthreads();
  aggv(WvC, bv2, us, rowa, red, tid);
  if (tid<128) rowb[tid]=gelu_f(rowa[tid]);
  __syncthreads();
  gemv128(out_nw, out_nb, rowb, rowa, red, tid);
  rowmode2(rowa, x1, xe, ln_ng, ln_nbeta, skip_n[0], xA, lane, wid);
  // pred-side layer-0 output row (same for all p of this b)
  gemv128(Wnv, bnv, x1, rowa, red, tid);
  if (tid<128) rowb[tid]=gelu_f(rowa[tid]);
  __syncthreads();
  gemv128(out_pw, out_pb, rowb, W0s, red, tid);
  // ======== layer 1 ========
  gemv512(Wcomb+65536, bcomb+512, xA, us, tid);
  const float sp0 = sigm(skip_p[0]), omsp = 1.f - sp0;
  const float2 W02 = ((const float2*)W0s)[lane];
  const float2 g02 = ((const float2*)ln_pg)[lane];
  const float2 b02 = ((const float2*)ln_pbeta)[lane];
  // pass A: scores + cache m1,i1
  for (int p=wid; p<106; p+=4){
    const float2 a = ((const float2*)(A1+p*128))[lane];
    const float2 u = ((const float2*)(Ub+p*128))[lane];
    float inv = inv0[p];
    float rx = (a.x+bv.x)*inv*gA2.x + bA2.x + u.x + V2.x;
    float ry = (a.y+bv.y)*inv*gA2.y + bA2.y + u.y + V2.y;
    float tx = sp0*W02.x + omsp*rx + u.x + V2.x;
    float ty = sp0*W02.y + omsp*ry + u.y + V2.y;
    float m = wsum(tx+ty)*(1.f/128.f);
    float dx=tx-m, dy=ty-m;
    float var = wsum(dx*dx+dy*dy)*(1.f/128.f);
    float iv2 = rsqrtf(var+1e-5f);
    if (lane==0){ m1s[p]=m; i1s[p]=iv2; }
    float r1 = elu_f(dx*iv2*g02.x+b02.x);
    float r2 = elu_f(dy*iv2*g02.y+b02.y);
    const float2 u0=((const float2*)us)[lane], u1=((const float2*)us)[64+lane];
    const float2 u2=((const float2*)us)[128+lane], u3=((const float2*)us)[192+lane];
    float s0=wsum(r1*u0.x+r2*u0.y);
    float s1=wsum(r1*u1.x+r2*u1.y);
    float s2=wsum(r1*u2.x+r2*u2.y);
    float s3=wsum(r1*u3.x+r2*u3.y);
    if (lane==0){ ss[p]=s0; ss[128+p]=s1; ss[256+p]=s2; ss[384+p]=s3; }
  }
  __syncthreads();
  softmax106(ss, lane, wid);
  __syncthreads();
  // pass B
  {
    float2 ya0=make_float2(0.f,0.f), ya1=ya0, ya2=ya0, ya3=ya0;
    for (int p=wid; p<106; p+=4){
      const float2 a = ((const float2*)(A1+p*128))[lane];
      const float2 u = ((const float2*)(Ub+p*128))[lane];
      float inv = inv0[p];
      float rx = (a.x+bv.x)*inv*gA2.x + bA2.x + u.x + V2.x;
      float ry = (a.y+bv.y)*inv*gA2.y + bA2.y + u.y + V2.y;
      float tx = sp0*W02.x + omsp*rx + u.x + V2.x;
      float ty = sp0*W02.y + omsp*ry + u.y + V2.y;
      float m = m1s[p], iv2 = i1s[p];
      float r1 = elu_f((tx-m)*iv2*g02.x+b02.x);
      float r2 = elu_f((ty-m)*iv2*g02.y+b02.y);
      float al0=ss[p], al1=ss[128+p], al2=ss[256+p], al3=ss[384+p];
      ya0.x+=al0*r1; ya0.y+=al0*r2; ya1.x+=al1*r1; ya1.y+=al1*r2;
      ya2.x+=al2*r1; ya2.y+=al2*r2; ya3.x+=al3*r1; ya3.y+=al3*r2;
    }
    float2* rw = (float2*)red2[wid];
    rw[lane]=ya0; rw[64+lane]=ya1; rw[128+lane]=ya2; rw[192+lane]=ya3;
  }
  __syncthreads();
  for (int idx=tid; idx<512; idx+=256)
    us[idx]=red2[0][idx]+red2[1][idx]+red2[2][idx]+red2[3][idx];
  __syncthreads();
  aggv(WvC+16384, bv2+128, us, rowa, red, tid);
  if (tid<128) rowb[tid]=gelu_f(rowa[tid]);
  __syncthreads();
  gemv128(out_nw+16384, out_nb+128, rowb, rowa, red, tid);
  rowmode2(rowa, xA, xA, ln_ng+128, ln_nbeta+128, skip_n[1], rowb, lane, wid);
  // logits
  if (wid==0){
    float xv0=rowb[lane], xv1=rowb[lane+64];
    float a0=xv0*cls_w[lane*2]   + xv1*cls_w[(lane+64)*2];
    float a1=xv0*cls_w[lane*2+1] + xv1*cls_w[(lane+64)*2+1];
    a0=wsum(a0); a1=wsum(a1);
    if (lane==0){ out[b*2]=a0+cls_b[0]; out[b*2+1]=a1+cls_b[1]; }
  }
}

__global__ __launch_bounds__(256) void prep0(
  const float* __restrict__ ctx_w, const float* __restrict__ ctx_b,
  const float* __restrict__ enc_w,
  const float* __restrict__ proj_w, const float* __restrict__ proj_b,
  const float* __restrict__ base_embs,
  const float* __restrict__ fus_w, const float* __restrict__ fus_b,
  const float* __restrict__ lin_pw, const float* __restrict__ lin_pb,
  const float* __restrict__ kqv_nw, const float* __restrict__ kqv_nb,
  const float* __restrict__ kqv_pw, const float* __restrict__ kqv_pb,
  const float* __restrict__ a_rel, const float* __restrict__ m_rel,
  const float* __restrict__ p_rel,
  float* __restrict__ Wcomb, float* __restrict__ bcomb,
  float* __restrict__ WvC, float* __restrict__ bv2,
  float* __restrict__ Wnv, float* __restrict__ bnv,
  float* __restrict__ Wbig, float* __restrict__ bVb, float* __restrict__ bB1,
  float* __restrict__ Ub, float* __restrict__ A1, float* __restrict__ sa1)
{
  const int blk=blockIdx.x, tid=threadIdx.x, lane=tid&63, wid=tid>>6;
  __shared__ float sh[2048];
  __shared__ float row1[128], row2[128], row3[128];
  __shared__ float red[256];
  if (blk < 16){
    // Wcomb/bcomb for (l, h, cc-half): scores fully folded, prescaled
    int l=blk>>3, jq=blk&7, h=jq>>1, cc0=(jq&1)*64;
    float* wk = sh; // [32 e][64 cl]
    float ps = p_rel[(l*2+1)*4+h]*0.17677669529663687f;
    for (int idx=tid; idx<2048; idx+=256){
      int e=idx>>6, cl=idx&63;
      float acc=0.f;
#pragma unroll
      for (int d=0;d<32;d++)
        acc += kqv_pw[(long)l*49152 + (cc0+cl)*384 + h*32 + d]
             * a_rel[((l*2+1)*4+h)*1024 + d*32 + e];
      wk[e*64+cl]=acc*ps;
    }
    __syncthreads();
    for (int idx=tid; idx<8192; idx+=256){
      int c=idx>>6, jl=idx&63;
      float acc=0.f;
#pragma unroll
      for (int e=0;e<32;e++) acc += kqv_nw[(long)l*49152 + c*384 + 128 + h*32 + e]*wk[e*64+jl];
      Wcomb[(long)l*65536 + c*512 + h*128 + cc0 + jl]=acc;
    }
    if (tid<64){
      float acc=0.f;
#pragma unroll
      for (int e=0;e<32;e++) acc += kqv_nb[l*384 + 128 + h*32 + e]*wk[e*64+tid];
      bcomb[l*512 + h*128 + cc0 + tid]=acc;
    }
  } else if (blk < 24){
    // WvC[l][h*128+cc][d] = sum_dp Wv_p[cc][h*32+dp]*m_rel[l,1,h,dp,d]
    int t=blk-16, l=t>>2, h=t&3;
    float* rl = sh;
    for (int i=tid;i<1024;i+=256) rl[i]=m_rel[((l*2+1)*4+h)*1024+i];
    __syncthreads();
    for (int idx=tid; idx<4096; idx+=256){
      int cc=idx>>5, d=idx&31;
      float acc=0.f;
#pragma unroll
      for (int dp=0;dp<32;dp++) acc += kqv_pw[(long)l*49152 + cc*384 + 256 + h*32 + dp]*rl[dp*32+d];
      WvC[l*16384 + (h*128+cc)*32 + d]=acc;
    }
  } else if (blk==24){
    {
      int l=tid>>7, j=tid&127, h=(j>>5)&3, d=j&31;
      float acc=0.f;
#pragma unroll
      for (int dp=0;dp<32;dp++) acc += kqv_pb[l*384+256+h*32+dp]*m_rel[((l*2+1)*4+h)*1024+dp*32+d];
      bv2[l*128+j]=acc;
    }
    if (tid < 128){
      int j=tid, h=j>>5, d=j&31;
      float acc=0.f;
#pragma unroll
      for (int dp=0;dp<32;dp++) acc += kqv_nb[256+h*32+dp]*m_rel[h*1024+dp*32+d];
      bnv[j]=acc;
    }
  } else if (blk < 29){
    // Wnv (layer0, edge news->pred)
    int h=blk-25;
    float* rl=sh;
    for (int i=tid;i<1024;i+=256) rl[i]=m_rel[h*1024+i];
    __syncthreads();
    for (int idx=tid; idx<4096; idx+=256){
      int c=idx>>5, d=idx&31;
      float acc=0.f;
#pragma unroll
      for (int dp=0;dp<32;dp++) acc += kqv_nw[c*384+256+h*32+dp]*rl[dp*32+d];
      Wnv[c*128 + h*32 + d]=acc;
    }
  } else if (blk==29){
    // bVb = ctx_b@fusW2 ; bB1 = bVb@lin_pw + lin_pb
    int j=tid&127, kg=tid>>7;
    float acc=0.f;
#pragma unroll 4
    for (int i=0;i<64;i++) acc += ctx_b[kg*64+i]*fus_w[(128+kg*64+i)*128+j];
    red[tid]=acc; __syncthreads();
    if (tid<128){ float v=red[tid]+red[tid+128]; bVb[tid]=v; row1[tid]=v; }
    __syncthreads();
    acc=0.f;
#pragma unroll 4
    for (int i=0;i<64;i++) acc += row1[kg*64+i]*lin_pw[(kg*64+i)*128+j];
    red[tid]=acc; __syncthreads();
    if (tid<128) bB1[tid]=red[tid]+red[tid+128]+lin_pb[tid];
  } else if (blk < 158){
    // Wbig[k][0:128]=enc_w row; [128:256]=ctx_w@fusW2; [256:384]=that@lin_pw
    int k0=(blk-30)*8;
    int j=tid&127, kg=tid>>7;
    for (int rr=0; rr<8; rr++){
      int k=k0+rr;
      if (tid<128){ row1[tid]=ctx_w[(long)k*128+tid]; Wbig[(long)k*384+tid]=enc_w[(long)k*128+tid]; }
      __syncthreads();
      float acc=0.f;
#pragma unroll 4
      for (int i=0;i<64;i++) acc += row1[kg*64+i]*fus_w[(128+kg*64+i)*128+j];
      red[tid]=acc; __syncthreads();
      if (tid<128){ float v=red[tid]+red[tid+128]; Wbig[(long)k*384+128+tid]=v; row2[tid]=v; }
      __syncthreads();
      acc=0.f;
#pragma unroll 4
      for (int i=0;i<64;i++) acc += row2[kg*64+i]*lin_pw[(kg*64+i)*128+j];
      red[tid]=acc; __syncthreads();
      if (tid<128) Wbig[(long)k*384+256+tid]=red[tid]+red[tid+128];
      __syncthreads();
    }
  } else {
    // pred chain: one block per p: base->proj->fus(Ub)->lin_pw->center(A1,sa1)
    int p = blk-158;
    float* xs1=sh;
    int j=tid&127, kg=tid>>7;
    for (int i=tid;i<1024;i+=256) xs1[i]=base_embs[(long)p*1024+i];
    __syncthreads();
    float acc=0.f;
#pragma unroll 4
    for (int k=0;k<512;k++) acc += xs1[kg*512+k]*proj_w[(long)(kg*512+k)*128+j];
    red[tid]=acc; __syncthreads();
    if (tid<128) row1[tid]=red[tid]+red[tid+128]+proj_b[tid];
    __syncthreads();
    acc=0.f;
#pragma unroll 4
    for (int i=0;i<64;i++) acc += row1[kg*64+i]*fus_w[(long)(kg*64+i)*128+j];
    red[tid]=acc; __syncthreads();
    if (tid<128){ float v=red[tid]+red[tid+128]+fus_b[tid]; row2[tid]=v; Ub[(long)p*128+tid]=v; }
    __syncthreads();
    acc=0.f;
#pragma unroll 4
    for (int i=0;i<64;i++) acc += row2[kg*64+i]*lin_pw[(long)(kg*64+i)*128+j];
    red[tid]=acc; __syncthreads();
    if (tid<128) row3[tid]=red[tid]+red[tid+128];
    __syncthreads();
    if (wid==0){
      float t0=row3[lane], t1=row3[lane+64];
      float m=wsum(t0+t1)*(1.f/128.f);
      t0-=m; t1-=m;
      float ssq=wsum(t0*t0+t1*t1);
      A1[(long)p*128+lane]=t0; A1[(long)p*128+lane+64]=t1;
      if (lane==0) sa1[p]=ssq;
    }
  }
}

__global__ __launch_bounds__(256) void prep1(
  const float* __restrict__ news_emb, const float* __restrict__ Wbig,
  const float* __restrict__ enc_b, const float* __restrict__ enc_g, const float* __restrict__ enc_beta,
  const float* __restrict__ bVb, const float* __restrict__ bB1,
  float* __restrict__ xn_enc, float* __restrict__ Vv, float* __restrict__ B1v, float* __restrict__ sb1)
{
  __shared__ __align__(16) float xs[4][1024];
  __shared__ float red2[1024];
  __shared__ float rows[4][128];
  const int r0=blockIdx.x*4, tid=threadIdx.x, lane=tid&63, wid=tid>>6;
  for (int r=0;r<4;r++){
    float4 v = *reinterpret_cast<const float4*>(news_emb + (long)(r0+r)*1024 + tid*4);
    *reinterpret_cast<float4*>(&xs[r][tid*4]) = v;
  }
  __syncthreads();
  const int j=tid&127, kg=tid>>7;
  for (int chunk=0; chunk<3; chunk++){
    const float* Wp = Wbig + (long)(kg*512)*384 + chunk*128 + j;
    float a0=0.f,a1=0.f,a2=0.f,a3=0.f;
#pragma unroll 2
    for (int k=0;k<512;k++){
      float w = Wp[(long)k*384];
      a0+=xs[0][kg*512+k]*w; a1+=xs[1][kg*512+k]*w;
      a2+=xs[2][kg*512+k]*w; a3+=xs[3][kg*512+k]*w;
    }
    red2[(kg*4+0)*128+j]=a0; red2[(kg*4+1)*128+j]=a1;
    red2[(kg*4+2)*128+j]=a2; red2[(kg*4+3)*128+j]=a3;
    __syncthreads();
    if (kg==0){
#pragma unroll
      for (int r=0;r<4;r++) rows[r][j]=red2[r*128+j]+red2[(4+r)*128+j];
    }
    __syncthreads();
    if (chunk==0){
      float t0=rows[wid][lane]+enc_b[lane], t1=rows[wid][lane+64]+enc_b[lane+64];
      float m=wsum(t0+t1)*(1.f/128.f);
      float d0=t0-m,d1=t1-m;
      float var=wsum(d0*d0+d1*d1)*(1.f/128.f);
      float inv=rsqrtf(var+1e-5f);
      xn_enc[(long)(r0+wid)*128+lane]   =elu_f(d0*inv*enc_g[lane]   +enc_beta[lane]);
      xn_enc[(long)(r0+wid)*128+lane+64]=elu_f(d1*inv*enc_g[lane+64]+enc_beta[lane+64]);
    } else if (chunk==1){
      for (int idx=tid; idx<512; idx+=256){
        int r=idx>>7, jj=idx&127;
        Vv[(long)(r0+r)*128+jj]=rows[r][jj]+bVb[jj];
      }
    } else {
      float t0=rows[wid][lane]+bB1[lane], t1=rows[wid][lane+64]+bB1[lane+64];
      float m=wsum(t0+t1)*(1.f/128.f);
      t0-=m; t1-=m;
      float ssq=wsum(t0*t0+t1*t1);
      B1v[(long)(r0+wid)*128+lane]=t0; B1v[(long)(r0+wid)*128+lane+64]=t1;
      if (lane==0) sb1[r0+wid]=ssq;
    }
    __syncthreads();
  }
}

// att[b][i][j][h] = 1/107 everywhere except [b][0][1..106][:] = 1/217088
// one block per b: 11449 float4 writes, no modulo
__global__ __launch_bounds__(256) void fill_att2(float4* __restrict__ att4){
  const float v1 = 1.f/107.f, v2 = 1.f/217088.f;
  long base = (long)blockIdx.x*11449;
  for (int i=threadIdx.x; i<11449; i+=256){
    float v = (i>=1 && i<107) ? v2 : v1;
    att4[base+i] = make_float4(v,v,v,v);
  }
}

extern "C" void kernel_launch(void* const* d_in, const int* in_sizes, int n_in,
                              void* d_out, int out_size, void* d_ws, size_t ws_size,
                              hipStream_t stream) {
  const float* news_emb = (const float*)d_in[0];
  const float* base_embs= (const float*)d_in[1];
  const float* ctx_w  = (const float*)d_in[2];
  const float* ctx_b  = (const float*)d_in[3];
  const float* proj_w = (const float*)d_in[4];
  const float* proj_b = (const float*)d_in[5];
  const float* fus_w  = (const float*)d_in[6];
  const float* fus_b  = (const float*)d_in[7];
  const float* enc_w  = (const float*)d_in[8];
  const float* enc_b  = (const float*)d_in[9];
  const float* enc_g  = (const float*)d_in[10];
  const float* enc_beta=(const float*)d_in[11];
  const float* lin_nw = (const float*)d_in[12];
  const float* lin_nb = (const float*)d_in[13];
  const float* lin_ng = (const float*)d_in[14];
  const float* lin_nbeta=(const float*)d_in[15];
  const float* kqv_nw = (const float*)d_in[16];
  const float* kqv_nb = (const float*)d_in[17];
  const float* out_nw = (const float*)d_in[18];
  const float* out_nb = (const float*)d_in[19];
  const float* skip_n = (const float*)d_in[20];
  const float* ln_ng  = (const float*)d_in[21];
  const float* ln_nbeta=(const float*)d_in[22];
  const float* lin_pw = (const float*)d_in[23];
  const float* lin_pb = (const float*)d_in[24];
  const float* lin_pg = (const float*)d_in[25];
  const float* lin_pbeta=(const float*)d_in[26];
  const float* kqv_pw = (const float*)d_in[27];
  const float* kqv_pb = (const float*)d_in[28];
  const float* out_pw = (const float*)d_in[29];
  const float* out_pb = (const float*)d_in[30];
  const float* skip_p = (const float*)d_in[31];
  const float* ln_pg  = (const float*)d_in[32];
  const float* ln_pbeta=(const float*)d_in[33];
  const float* a_rel  = (const float*)d_in[34];
  const float* m_rel  = (const float*)d_in[35];
  const float* p_rel  = (const float*)d_in[36];
  const float* cls_w  = (const float*)d_in[37];
  const float* cls_b  = (const float*)d_in[38];
  (void)in_sizes; (void)n_in; (void)out_size; (void)d_ws; (void)ws_size;

  float* out = (float*)d_out;
  float* S = out + 4096;            // att region as scratch; constant-filled last
  float* xn_enc = S + 0;            // 2048*128
  float* Vv     = S + 262144;       // 2048*128
  float* B1v    = S + 524288;       // 2048*128
  float* sb1    = S + 786432;       // 2048
  float* Ub     = S + 788480;       // 106*128
  float* A1     = S + 802048;       // 106*128
  float* sa1    = S + 815616;       // 106 (pad to 128)
  float* WvC    = S + 815744;       // 2*512*32
  float* bv2    = S + 848512;       // 2*128
  float* Wnv    = S + 848768;       // 128*128
  float* bnv    = S + 865152;       // 128
  float* Wcomb  = S + 865280;       // 2*128*512
  float* bcomb  = S + 996352;       // 2*512
  float* Wbig   = S + 997376;       // 1024*384
  float* bVb    = S + 1390592;      // 128
  float* bB1    = S + 1390720;      // 128

  dim3 blk(256);
  prep0<<<264,blk,0,stream>>>(ctx_w,ctx_b,enc_w,proj_w,proj_b,base_embs,
      fus_w,fus_b,lin_pw,lin_pb,kqv_nw,kqv_nb,kqv_pw,kqv_pb,a_rel,m_rel,p_rel,
      Wcomb,bcomb,WvC,bv2,Wnv,bnv,Wbig,bVb,bB1,Ub,A1,sa1);
  prep1<<<512,blk,0,stream>>>(news_emb,Wbig,enc_b,enc_g,enc_beta,bVb,bB1,
      xn_enc,Vv,B1v,sb1);
  mega<<<2048,blk,0,stream>>>(xn_enc,Vv,B1v,sb1,Ub,A1,sa1,Wcomb,bcomb,WvC,bv2,Wnv,bnv,
      lin_nw,lin_nb,lin_ng,lin_nbeta,lin_pg,lin_pbeta,ln_pg,ln_pbeta,
      out_nw,out_nb,out_pw,out_pb,skip_n,skip_p,ln_ng,ln_nbeta,cls_w,cls_b,out);
  fill_att2<<<2048,blk,0,stream>>>(reinterpret_cast<float4*>(S));
}

// Round 5
// 503.077 us; speedup vs baseline: 2.2137x; 1.1684x over previous
//
#include <hip/hip_runtime.h>
#include <math.h>

// B=2048, C=128, H=4, L=2, P=106, D=32
// 4 launches: PREP0 (weight folds + pred chain), PREP1 (news K=1024 pass, direct
// enc_w/ctx_w + chained small gemvs), MEGA (NB=4 b's per block, wave=b,
// transposed pass-A with lane=p -> no per-p shfl reductions), FILL (const att).

#define DEVFN __device__ __forceinline__

DEVFN float wsum(float v){
#pragma unroll
  for (int o=32;o;o>>=1) v += __shfl_xor(v,o);
  return v;
}
DEVFN float wmaxr(float v){
#pragma unroll
  for (int o=32;o;o>>=1) v = fmaxf(v,__shfl_xor(v,o));
  return v;
}
DEVFN float gelu_f(float x){ return 0.5f*x*(1.f+erff(x*0.70710678118654752f)); }
DEVFN float elu_f(float x){ return x>0.f?x:expm1f(x); }
DEVFN float sigm(float x){ return 1.f/(1.f+expf(-x)); }

// ---- block-wide NB=4 gemv helpers (256 threads) ----
// outs[r][j] = sum_k xs[r][k]*W[k*128+j] + bias[j]
DEVFN void gemv128x4(const float* __restrict__ W, const float* __restrict__ bias,
    const float* xs, float* outs, float* redL, int tid){
  __syncthreads();
  const int j=tid&127, kg=tid>>7;
  const float* Wp = W + (kg*64)*128 + j;
  float a0=0.f,a1=0.f,a2=0.f,a3=0.f;
#pragma unroll 4
  for (int k=0;k<64;k++){
    float wv=Wp[k*128];
    a0+=xs[kg*64+k]*wv; a1+=xs[128+kg*64+k]*wv;
    a2+=xs[256+kg*64+k]*wv; a3+=xs[384+kg*64+k]*wv;
  }
  redL[tid]=a0; redL[256+tid]=a1; redL[512+tid]=a2; redL[768+tid]=a3;
  __syncthreads();
  for (int i=tid;i<512;i+=256){
    int r=i>>7, jj=i&127;
    outs[r*128+jj]=redL[r*256+jj]+redL[r*256+128+jj]+bias[jj];
  }
  __syncthreads();
}

// us[r][0:512] = xs[r][0:128] @ W[128][512] + bias
DEVFN void gemv512x4(const float* __restrict__ W, const float* __restrict__ bias,
    const float* xs, float* us, int tid){
  __syncthreads();
  float b0=bias[tid], b1=bias[256+tid];
  float a00=b0,a10=b0,a20=b0,a30=b0, a01=b1,a11=b1,a21=b1,a31=b1;
#pragma unroll 4
  for (int k=0;k<128;k++){
    float w0=W[k*512+tid], w1=W[k*512+256+tid];
    float v0=xs[k],v1=xs[128+k],v2=xs[256+k],v3=xs[384+k];
    a00+=v0*w0; a01+=v0*w1; a10+=v1*w0; a11+=v1*w1;
    a20+=v2*w0; a21+=v2*w1; a30+=v3*w0; a31+=v3*w1;
  }
  us[tid]=a00; us[256+tid]=a01; us[512+tid]=a10; us[768+tid]=a11;
  us[1024+tid]=a20; us[1280+tid]=a21; us[1536+tid]=a30; us[1792+tid]=a31;
  __syncthreads();
}

// outs[r][h*32+d] = sum_cc Ys[r][h*128+cc]*WvC[(h*128+cc)*32+d] + bv[h*32+d]
DEVFN void aggvx4(const float* __restrict__ WvC, const float* __restrict__ bv,
    const float* Ys, float* outs, float* redL, int tid){
  __syncthreads();
  const int d=tid&31, h=(tid>>5)&3, cg=tid>>7;
  const float* Wp = WvC + (h*128+cg*64)*32 + d;
  const float* y0 = Ys + h*128 + cg*64;
  float a0=0.f,a1=0.f,a2=0.f,a3=0.f;
#pragma unroll 4
  for (int i=0;i<64;i++){
    float wv=Wp[i*32];
    a0+=y0[i]*wv; a1+=y0[512+i]*wv; a2+=y0[1024+i]*wv; a3+=y0[1536+i]*wv;
  }
  redL[tid]=a0; redL[256+tid]=a1; redL[512+tid]=a2; redL[768+tid]=a3;
  __syncthreads();
  for (int i=tid;i<512;i+=256){
    int r=i>>7, jj=i&127;
    outs[r*128+jj]=redL[r*256+jj]+redL[r*256+128+jj]+bv[jj];
  }
  __syncthreads();
}

// out = elu(LN(sn*A + (1-sn)*Bx + R; g,be))  -- per-wave, no barriers
DEVFN void rowmode2w(const float* A, const float* Bx, const float* R,
  const float* __restrict__ g, const float* __restrict__ be, float skipval,
  float* outr, int lane){
  float sn=sigm(skipval), os=1.f-sn;
  float t0=sn*A[lane]+os*Bx[lane]+R[lane];
  float t1=sn*A[lane+64]+os*Bx[lane+64]+R[lane+64];
  float m=wsum(t0+t1)*(1.f/128.f);
  float d0=t0-m,d1=t1-m;
  float var=wsum(d0*d0+d1*d1)*(1.f/128.f);
  float inv=rsqrtf(var+1e-5f);
  outr[lane]=elu_f(d0*inv*g[lane]+be[lane]);
  outr[lane+64]=elu_f(d1*inv*g[lane+64]+be[lane+64]);
}

// softmax over p-pair held in (lane, lane+64): write alpha to dst[0:128]
DEVFN void smx(float sA, float sB, bool val1, int lane, float* dst){
  float mx = wmaxr(fmaxf(sA, val1? sB : -1e30f));
  float e0 = expf(sA-mx), e1 = val1? expf(sB-mx) : 0.f;
  float den = wsum(e0+e1);
  float r = 1.f/den;
  dst[lane]=e0*r;
  if (val1) dst[lane+64]=e1*r;
}

__global__ __launch_bounds__(256,2) void mega(
  const float* __restrict__ xn_enc_g, const float* __restrict__ Vv_g,
  const float* __restrict__ B1v_g, const float* __restrict__ sb1_g,
  const float* __restrict__ Ub, const float* __restrict__ A1, const float* __restrict__ sa1,
  const float* __restrict__ Wcomb, const float* __restrict__ bcomb,
  const float* __restrict__ WvC, const float* __restrict__ bv2,
  const float* __restrict__ Wnv, const float* __restrict__ bnv,
  const float* __restrict__ lin_nw, const float* __restrict__ lin_nb,
  const float* __restrict__ lin_ng, const float* __restrict__ lin_nbeta,
  const float* __restrict__ lin_pg, const float* __restrict__ lin_pbeta,
  const float* __restrict__ ln_pg, const float* __restrict__ ln_pbeta,
  const float* __restrict__ out_nw, const float* __restrict__ out_nb,
  const float* __restrict__ out_pw, const float* __restrict__ out_pb,
  const float* __restrict__ skip_n, const float* __restrict__ skip_p,
  const float* __restrict__ ln_ng, const float* __restrict__ ln_nbeta,
  const float* __restrict__ cls_w, const float* __restrict__ cls_b,
  float* __restrict__ out)
{
  __shared__ float xe[512], x1[512], xA[512], W0s[512], Bv[512], Vvs[512];
  __shared__ float scratch[2048];   // us (score weights) then Ys, per-b 512
  __shared__ float POOL[2048];      // alpha [4][4][128] OR redL[1024]+rowa[512]+rowb[512]
  __shared__ float inv0[512], m1s[512], i1s[512];
  __shared__ float gAs[128], bAs[128], g0s[128], b0s[128];
  float* redL = POOL;
  float* rowa = POOL + 1024;
  float* rowb = POOL + 1536;
  float* ssA  = POOL;               // alpha: [w][h][p]
  const int tid=threadIdx.x, lane=tid&63, w=tid>>6;
  const int bbase = blockIdx.x*4;
  const int b = bbase + w;
  for (int i=tid;i<512;i+=256){
    xe[i]=xn_enc_g[(long)bbase*128+i];
    Bv[i]=B1v_g[(long)bbase*128+i];
    Vvs[i]=Vv_g[(long)bbase*128+i];
  }
  if (tid<128){ gAs[tid]=lin_pg[tid]; bAs[tid]=lin_pbeta[tid]; g0s[tid]=ln_pg[tid]; b0s[tid]=ln_pbeta[tid]; }
  gemv128x4(lin_nw, lin_nb, xe, rowa, redL, tid);
  { // x1 = LN(rowa)+xe per wave
    const float* rw = rowa + w*128;
    float t0=rw[lane], t1=rw[lane+64];
    float m=wsum(t0+t1)*(1.f/128.f);
    float d0=t0-m,d1=t1-m;
    float var=wsum(d0*d0+d1*d1)*(1.f/128.f);
    float inv=rsqrtf(var+1e-5f);
    x1[w*128+lane]   =d0*inv*lin_ng[lane]   +lin_nbeta[lane]   +xe[w*128+lane];
    x1[w*128+lane+64]=d1*inv*lin_ng[lane+64]+lin_nbeta[lane+64]+xe[w*128+lane+64];
  }
  gemv512x4(Wcomb, bcomb, x1, scratch, tid);
  // ======== layer 0, transposed pass A (lane = p, p-pair) ========
  const float sb = sb1_g[b];
  const int p0=lane, p1=lane+64;
  const int p1c = (p1<106)? p1 : 105;
  const bool val1 = (p1<106);
  const float2* A12=(const float2*)A1;
  const float2* Ub2=(const float2*)Ub;
  const float2* BvW=(const float2*)(Bv+w*128);
  const float2* VvW=(const float2*)(Vvs+w*128);
  const float2* gAW=(const float2*)gAs;
  const float2* bAW=(const float2*)bAs;
  const float2* g0W=(const float2*)g0s;
  const float2* b0W=(const float2*)b0s;
  const float2* UsW=(const float2*)(scratch+w*512);
  float iv0, iv1;
  {
    float d0=0.f,d1=0.f;
#pragma unroll 4
    for (int c=0;c<64;c++){
      float2 a0=A12[p0*64+c], a1=A12[p1c*64+c], bb=BvW[c];
      d0 += a0.x*bb.x + a0.y*bb.y;
      d1 += a1.x*bb.x + a1.y*bb.y;
    }
    iv0 = rsqrtf((sa1[p0]+2.f*d0+sb)*(1.f/128.f)+1e-5f);
    iv1 = rsqrtf((sa1[p1c]+2.f*d1+sb)*(1.f/128.f)+1e-5f);
    inv0[w*128+p0]=iv0;
    if (val1) inv0[w*128+p1]=iv1;
  }
  {
    float s00=0,s01=0,s02=0,s03=0,s10=0,s11=0,s12=0,s13=0;
#pragma unroll 2
    for (int c=0;c<64;c++){
      float2 a0=A12[p0*64+c], a1=A12[p1c*64+c];
      float2 u0=Ub2[p0*64+c], u1=Ub2[p1c*64+c];
      float2 bb=BvW[c], vv=VvW[c], ga=gAW[c], ba=bAW[c];
      float2 q0=UsW[c], q1=UsW[64+c], q2=UsW[128+c], q3=UsW[192+c];
      float x0=(a0.x+bb.x)*iv0*ga.x+ba.x+u0.x+vv.x;
      float y0=(a0.y+bb.y)*iv0*ga.y+ba.y+u0.y+vv.y;
      float x1v=(a1.x+bb.x)*iv1*ga.x+ba.x+u1.x+vv.x;
      float y1v=(a1.y+bb.y)*iv1*ga.y+ba.y+u1.y+vv.y;
      s00+=x0*q0.x+y0*q0.y; s01+=x0*q1.x+y0*q1.y; s02+=x0*q2.x+y0*q2.y; s03+=x0*q3.x+y0*q3.y;
      s10+=x1v*q0.x+y1v*q0.y; s11+=x1v*q1.x+y1v*q1.y; s12+=x1v*q2.x+y1v*q2.y; s13+=x1v*q3.x+y1v*q3.y;
    }
    smx(s00,s10,val1,lane, ssA+w*512+0);
    smx(s01,s11,val1,lane, ssA+w*512+128);
    smx(s02,s12,val1,lane, ssA+w*512+256);
    smx(s03,s13,val1,lane, ssA+w*512+384);
  }
  { // pass B (lane = c), accumulate Ys in regs, write own region of scratch
    const float2 bb=BvW[lane], vv=VvW[lane], ga=gAW[lane], ba=bAW[lane];
    float2 y0={0,0},y1={0,0},y2={0,0},y3={0,0};
    const float* al = ssA + w*512;
    for (int p=0;p<106;p++){
      float2 a=A12[p*64+lane], u=Ub2[p*64+lane];
      float iv=inv0[w*128+p];
      float rx=(a.x+bb.x)*iv*ga.x+ba.x+u.x+vv.x;
      float ry=(a.y+bb.y)*iv*ga.y+ba.y+u.y+vv.y;
      float a0=al[p],a1=al[128+p],a2=al[256+p],a3=al[384+p];
      y0.x+=a0*rx; y0.y+=a0*ry; y1.x+=a1*rx; y1.y+=a1*ry;
      y2.x+=a2*rx; y2.y+=a2*ry; y3.x+=a3*rx; y3.y+=a3*ry;
    }
    float2* Yw=(float2*)(scratch+w*512);
    Yw[lane]=y0; Yw[64+lane]=y1; Yw[128+lane]=y2; Yw[192+lane]=y3;
  }
  aggvx4(WvC, bv2, scratch, rowa, redL, tid);
  for (int i=tid;i<512;i+=256) rowb[i]=gelu_f(rowa[i]);
  gemv128x4(out_nw, out_nb, rowb, rowa, redL, tid);
  rowmode2w(rowa+w*128, x1+w*128, xe+w*128, ln_ng, ln_nbeta, skip_n[0], xA+w*128, lane);
  gemv128x4(Wnv, bnv, x1, rowa, redL, tid);
  for (int i=tid;i<512;i+=256) rowb[i]=gelu_f(rowa[i]);
  gemv128x4(out_pw, out_pb, rowb, W0s, redL, tid);
  // ======== layer 1 ========
  gemv512x4(Wcomb+65536, bcomb+512, xA, scratch, tid);
  const float sp0 = sigm(skip_p[0]), omsp=1.f-sp0;
  const float2* W0W=(const float2*)(W0s+w*128);
  float mA, ivA, mB, ivB;
  { // stats sub-pass
    float st0=0,sq0=0,st1=0,sq1=0;
#pragma unroll 2
    for (int c=0;c<64;c++){
      float2 a0=A12[p0*64+c], a1=A12[p1c*64+c];
      float2 u0=Ub2[p0*64+c], u1=Ub2[p1c*64+c];
      float2 bb=BvW[c], vv=VvW[c], ga=gAW[c], ba=bAW[c], w0=W0W[c];
      float x0=(a0.x+bb.x)*iv0*ga.x+ba.x+u0.x+vv.x;
      float y0=(a0.y+bb.y)*iv0*ga.y+ba.y+u0.y+vv.y;
      float x1v=(a1.x+bb.x)*iv1*ga.x+ba.x+u1.x+vv.x;
      float y1v=(a1.y+bb.y)*iv1*ga.y+ba.y+u1.y+vv.y;
      float t0=sp0*w0.x+omsp*x0+u0.x+vv.x;
      float t1=sp0*w0.y+omsp*y0+u0.y+vv.y;
      float t2=sp0*w0.x+omsp*x1v+u1.x+vv.x;
      float t3=sp0*w0.y+omsp*y1v+u1.y+vv.y;
      st0+=t0+t1; sq0+=t0*t0+t1*t1;
      st1+=t2+t3; sq1+=t2*t2+t3*t3;
    }
    mA=st0*(1.f/128.f); ivA=rsqrtf(fmaxf(sq0*(1.f/128.f)-mA*mA,0.f)+1e-5f);
    mB=st1*(1.f/128.f); ivB=rsqrtf(fmaxf(sq1*(1.f/128.f)-mB*mB,0.f)+1e-5f);
    m1s[w*128+p0]=mA; i1s[w*128+p0]=ivA;
    if (val1){ m1s[w*128+p1]=mB; i1s[w*128+p1]=ivB; }
  }
  { // scores sub-pass
    float s00=0,s01=0,s02=0,s03=0,s10=0,s11=0,s12=0,s13=0;
#pragma unroll 2
    for (int c=0;c<64;c++){
      float2 a0=A12[p0*64+c], a1=A12[p1c*64+c];
      float2 u0=Ub2[p0*64+c], u1=Ub2[p1c*64+c];
      float2 bb=BvW[c], vv=VvW[c], ga=gAW[c], ba=bAW[c], w0=W0W[c];
      float2 g0=g0W[c], b0v=b0W[c];
      float2 q0=UsW[c], q1=UsW[64+c], q2=UsW[128+c], q3=UsW[192+c];
      float x0=(a0.x+bb.x)*iv0*ga.x+ba.x+u0.x+vv.x;
      float y0=(a0.y+bb.y)*iv0*ga.y+ba.y+u0.y+vv.y;
      float x1v=(a1.x+bb.x)*iv1*ga.x+ba.x+u1.x+vv.x;
      float y1v=(a1.y+bb.y)*iv1*ga.y+ba.y+u1.y+vv.y;
      float t0=sp0*w0.x+omsp*x0+u0.x+vv.x;
      float t1=sp0*w0.y+omsp*y0+u0.y+vv.y;
      float t2=sp0*w0.x+omsp*x1v+u1.x+vv.x;
      float t3=sp0*w0.y+omsp*y1v+u1.y+vv.y;
      float r0=elu_f((t0-mA)*ivA*g0.x+b0v.x);
      float r1=elu_f((t1-mA)*ivA*g0.y+b0v.y);
      float r2=elu_f((t2-mB)*ivB*g0.x+b0v.x);
      float r3=elu_f((t3-mB)*ivB*g0.y+b0v.y);
      s00+=r0*q0.x+r1*q0.y; s01+=r0*q1.x+r1*q1.y; s02+=r0*q2.x+r1*q2.y; s03+=r0*q3.x+r1*q3.y;
      s10+=r2*q0.x+r3*q0.y; s11+=r2*q1.x+r3*q1.y; s12+=r2*q2.x+r3*q2.y; s13+=r2*q3.x+r3*q3.y;
    }
    smx(s00,s10,val1,lane, ssA+w*512+0);
    smx(s01,s11,val1,lane, ssA+w*512+128);
    smx(s02,s12,val1,lane, ssA+w*512+256);
    smx(s03,s13,val1,lane, ssA+w*512+384);
  }
  { // pass B layer 1
    const float2 bb=BvW[lane], vv=VvW[lane], ga=gAW[lane], ba=bAW[lane];
    const float2 w0=W0W[lane], g0=g0W[lane], b0v=b0W[lane];
    float2 y0={0,0},y1={0,0},y2={0,0},y3={0,0};
    const float* al = ssA + w*512;
    for (int p=0;p<106;p++){
      float2 a=A12[p*64+lane], u=Ub2[p*64+lane];
      float iv=inv0[w*128+p], m=m1s[w*128+p], i2=i1s[w*128+p];
      float rx=(a.x+bb.x)*iv*ga.x+ba.x+u.x+vv.x;
      float ry=(a.y+bb.y)*iv*ga.y+ba.y+u.y+vv.y;
      float tx=sp0*w0.x+omsp*rx+u.x+vv.x;
      float ty=sp0*w0.y+omsp*ry+u.y+vv.y;
      float r0=elu_f((tx-m)*i2*g0.x+b0v.x);
      float r1=elu_f((ty-m)*i2*g0.y+b0v.y);
      float a0=al[p],a1=al[128+p],a2=al[256+p],a3=al[384+p];
      y0.x+=a0*r0; y0.y+=a0*r1; y1.x+=a1*r0; y1.y+=a1*r1;
      y2.x+=a2*r0; y2.y+=a2*r1; y3.x+=a3*r0; y3.y+=a3*r1;
    }
    float2* Yw=(float2*)(scratch+w*512);
    Yw[lane]=y0; Yw[64+lane]=y1; Yw[128+lane]=y2; Yw[192+lane]=y3;
  }
  aggvx4(WvC+16384, bv2+128, scratch, rowa, redL, tid);
  for (int i=tid;i<512;i+=256) rowb[i]=gelu_f(rowa[i]);
  gemv128x4(out_nw+16384, out_nb+128, rowb, rowa, redL, tid);
  rowmode2w(rowa+w*128, xA+w*128, xA+w*128, ln_ng+128, ln_nbeta+128, skip_n[1], x1+w*128, lane);
  { // logits per wave
    float xv0=x1[w*128+lane], xv1=x1[w*128+lane+64];
    float a0=xv0*cls_w[lane*2]  +xv1*cls_w[(lane+64)*2];
    float a1=xv0*cls_w[lane*2+1]+xv1*cls_w[(lane+64)*2+1];
    a0=wsum(a0); a1=wsum(a1);
    if (lane==0){ out[b*2]=a0+cls_b[0]; out[b*2+1]=a1+cls_b[1]; }
  }
}

__global__ __launch_bounds__(256) void prep0(
  const float* __restrict__ ctx_w, const float* __restrict__ ctx_b,
  const float* __restrict__ proj_w, const float* __restrict__ proj_b,
  const float* __restrict__ base_embs,
  const float* __restrict__ fus_w, const float* __restrict__ fus_b,
  const float* __restrict__ lin_pw, const float* __restrict__ lin_pb,
  const float* __restrict__ kqv_nw, const float* __restrict__ kqv_nb,
  const float* __restrict__ kqv_pw, const float* __restrict__ kqv_pb,
  const float* __restrict__ a_rel, const float* __restrict__ m_rel,
  const float* __restrict__ p_rel,
  float* __restrict__ Wcomb, float* __restrict__ bcomb,
  float* __restrict__ WvC, float* __restrict__ bv2,
  float* __restrict__ Wnv, float* __restrict__ bnv,
  float* __restrict__ bVb, float* __restrict__ bB1,
  float* __restrict__ Ub, float* __restrict__ A1, float* __restrict__ sa1)
{
  const int blk=blockIdx.x, tid=threadIdx.x, lane=tid&63, wid=tid>>6;
  __shared__ float sh[2048];
  __shared__ float row1[128], row2[128], row3[128];
  __shared__ float red[256];
  if (blk < 16){
    int l=blk>>3, jq=blk&7, h=jq>>1, cc0=(jq&1)*64;
    float* wk = sh;
    float ps = p_rel[(l*2+1)*4+h]*0.17677669529663687f;
    for (int idx=tid; idx<2048; idx+=256){
      int e=idx>>6, cl=idx&63;
      float acc=0.f;
#pragma unroll
      for (int d=0;d<32;d++)
        acc += kqv_pw[(long)l*49152 + (cc0+cl)*384 + h*32 + d]
             * a_rel[((l*2+1)*4+h)*1024 + d*32 + e];
      wk[e*64+cl]=acc*ps;
    }
    __syncthreads();
    for (int idx=tid; idx<8192; idx+=256){
      int c=idx>>6, jl=idx&63;
      float acc=0.f;
#pragma unroll
      for (int e=0;e<32;e++) acc += kqv_nw[(long)l*49152 + c*384 + 128 + h*32 + e]*wk[e*64+jl];
      Wcomb[(long)l*65536 + c*512 + h*128 + cc0 + jl]=acc;
    }
    if (tid<64){
      float acc=0.f;
#pragma unroll
      for (int e=0;e<32;e++) acc += kqv_nb[l*384 + 128 + h*32 + e]*wk[e*64+tid];
      bcomb[l*512 + h*128 + cc0 + tid]=acc;
    }
  } else if (blk < 24){
    int t=blk-16, l=t>>2, h=t&3;
    float* rl = sh;
    for (int i=tid;i<1024;i+=256) rl[i]=m_rel[((l*2+1)*4+h)*1024+i];
    __syncthreads();
    for (int idx=tid; idx<4096; idx+=256){
      int cc=idx>>5, d=idx&31;
      float acc=0.f;
#pragma unroll
      for (int dp=0;dp<32;dp++) acc += kqv_pw[(long)l*49152 + cc*384 + 256 + h*32 + dp]*rl[dp*32+d];
      WvC[l*16384 + (h*128+cc)*32 + d]=acc;
    }
  } else if (blk==24){
    {
      int l=tid>>7, j=tid&127, h=(j>>5)&3, d=j&31;
      float acc=0.f;
#pragma unroll
      for (int dp=0;dp<32;dp++) acc += kqv_pb[l*384+256+h*32+dp]*m_rel[((l*2+1)*4+h)*1024+dp*32+d];
      bv2[l*128+j]=acc;
    }
    if (tid < 128){
      int j=tid, h=j>>5, d=j&31;
      float acc=0.f;
#pragma unroll
      for (int dp=0;dp<32;dp++) acc += kqv_nb[256+h*32+dp]*m_rel[h*1024+dp*32+d];
      bnv[j]=acc;
    }
  } else if (blk < 29){
    int h=blk-25;
    float* rl=sh;
    for (int i=tid;i<1024;i+=256) rl[i]=m_rel[h*1024+i];
    __syncthreads();
    for (int idx=tid; idx<4096; idx+=256){
      int c=idx>>5, d=idx&31;
      float acc=0.f;
#pragma unroll
      for (int dp=0;dp<32;dp++) acc += kqv_nw[c*384+256+h*32+dp]*rl[dp*32+d];
      Wnv[c*128 + h*32 + d]=acc;
    }
  } else if (blk==29){
    int j=tid&127, kg=tid>>7;
    float acc=0.f;
#pragma unroll 4
    for (int i=0;i<64;i++) acc += ctx_b[kg*64+i]*fus_w[(128+kg*64+i)*128+j];
    red[tid]=acc; __syncthreads();
    if (tid<128){ float v=red[tid]+red[tid+128]; bVb[tid]=v; row1[tid]=v; }
    __syncthreads();
    acc=0.f;
#pragma unroll 4
    for (int i=0;i<64;i++) acc += row1[kg*64+i]*lin_pw[(kg*64+i)*128+j];
    red[tid]=acc; __syncthreads();
    if (tid<128) bB1[tid]=red[tid]+red[tid+128]+lin_pb[tid];
  } else {
    // pred chain, one block per p
    int p = blk-30;
    float* xs1=sh;
    int j=tid&127, kg=tid>>7;
    for (int i=tid;i<1024;i+=256) xs1[i]=base_embs[(long)p*1024+i];
    __syncthreads();
    float acc=0.f;
#pragma unroll 4
    for (int k=0;k<512;k++) acc += xs1[kg*512+k]*proj_w[(long)(kg*512+k)*128+j];
    red[tid]=acc; __syncthreads();
    if (tid<128) row1[tid]=red[tid]+red[tid+128]+proj_b[tid];
    __syncthreads();
    acc=0.f;
#pragma unroll 4
    for (int i=0;i<64;i++) acc += row1[kg*64+i]*fus_w[(long)(kg*64+i)*128+j];
    red[tid]=acc; __syncthreads();
    if (tid<128){ float v=red[tid]+red[tid+128]+fus_b[tid]; row2[tid]=v; Ub[(long)p*128+tid]=v; }
    __syncthreads();
    acc=0.f;
#pragma unroll 4
    for (int i=0;i<64;i++) acc += row2[kg*64+i]*lin_pw[(long)(kg*64+i)*128+j];
    red[tid]=acc; __syncthreads();
    if (tid<128) row3[tid]=red[tid]+red[tid+128];
    __syncthreads();
    if (wid==0){
      float t0=row3[lane], t1=row3[lane+64];
      float m=wsum(t0+t1)*(1.f/128.f);
      t0-=m; t1-=m;
      float ssq=wsum(t0*t0+t1*t1);
      A1[(long)p*128+lane]=t0; A1[(long)p*128+lane+64]=t1;
      if (lane==0) sa1[p]=ssq;
    }
  }
}

__global__ __launch_bounds__(256) void prep1(
  const float* __restrict__ news_emb,
  const float* __restrict__ enc_w, const float* __restrict__ ctx_w,
  const float* __restrict__ fus_w, const float* __restrict__ lin_pw,
  const float* __restrict__ enc_b, const float* __restrict__ enc_g, const float* __restrict__ enc_beta,
  const float* __restrict__ bVb, const float* __restrict__ bB1,
  float* __restrict__ xn_enc, float* __restrict__ Vv, float* __restrict__ B1v, float* __restrict__ sb1)
{
  __shared__ __align__(16) float xs[4][1024];
  __shared__ float redL[1024];
  __shared__ float rowsC[4][128];
  __shared__ float Vraw[4][128];
  const int r0=blockIdx.x*4, tid=threadIdx.x, lane=tid&63, wid=tid>>6;
  for (int r=0;r<4;r++){
    float4 v=*(const float4*)(news_emb+(long)(r0+r)*1024+tid*4);
    *(float4*)(&xs[r][tid*4])=v;
  }
  __syncthreads();
  const int j=tid&127, kg=tid>>7;
  float ae0=0,ae1=0,ae2=0,ae3=0, ac0=0,ac1=0,ac2=0,ac3=0;
  {
    const float* We=enc_w+(long)(kg*512)*128+j;
    const float* Wc=ctx_w+(long)(kg*512)*128+j;
#pragma unroll 2
    for (int k=0;k<512;k++){
      float we=We[(long)k*128], wc=Wc[(long)k*128];
      float v0=xs[0][kg*512+k], v1=xs[1][kg*512+k], v2=xs[2][kg*512+k], v3=xs[3][kg*512+k];
      ae0+=v0*we; ae1+=v1*we; ae2+=v2*we; ae3+=v3*we;
      ac0+=v0*wc; ac1+=v1*wc; ac2+=v2*wc; ac3+=v3*wc;
    }
  }
  redL[tid]=ae0; redL[256+tid]=ae1; redL[512+tid]=ae2; redL[768+tid]=ae3;
  __syncthreads();
  { // enc LN + elu per wave (row wid)
    float t0=redL[wid*256+lane]+redL[wid*256+128+lane]+enc_b[lane];
    float t1=redL[wid*256+lane+64]+redL[wid*256+128+lane+64]+enc_b[lane+64];
    float m=wsum(t0+t1)*(1.f/128.f);
    float d0=t0-m,d1=t1-m;
    float var=wsum(d0*d0+d1*d1)*(1.f/128.f);
    float inv=rsqrtf(var+1e-5f);
    xn_enc[(long)(r0+wid)*128+lane]   =elu_f(d0*inv*enc_g[lane]   +enc_beta[lane]);
    xn_enc[(long)(r0+wid)*128+lane+64]=elu_f(d1*inv*enc_g[lane+64]+enc_beta[lane+64]);
  }
  __syncthreads();
  redL[tid]=ac0; redL[256+tid]=ac1; redL[512+tid]=ac2; redL[768+tid]=ac3;
  __syncthreads();
  for (int i=tid;i<512;i+=256){
    int r=i>>7,jj=i&127;
    rowsC[r][jj]=redL[r*256+jj]+redL[r*256+128+jj];
  }
  __syncthreads();
  { // Vraw = rowsC @ fusW2
    const float* Wf=fus_w+(128+kg*64)*128+j;
    float a0=0,a1=0,a2=0,a3=0;
#pragma unroll 4
    for (int i=0;i<64;i++){
      float wv=Wf[i*128];
      a0+=rowsC[0][kg*64+i]*wv; a1+=rowsC[1][kg*64+i]*wv;
      a2+=rowsC[2][kg*64+i]*wv; a3+=rowsC[3][kg*64+i]*wv;
    }
    redL[tid]=a0; redL[256+tid]=a1; redL[512+tid]=a2; redL[768+tid]=a3;
  }
  __syncthreads();
  for (int i=tid;i<512;i+=256){
    int r=i>>7,jj=i&127;
    float v=redL[r*256+jj]+redL[r*256+128+jj];
    Vraw[r][jj]=v;
    Vv[(long)(r0+r)*128+jj]=v+bVb[jj];
  }
  __syncthreads();
  { // B1 = Vraw @ lin_pw + bB1 -> center
    const float* Wl=lin_pw+(kg*64)*128+j;
    float a0=0,a1=0,a2=0,a3=0;
#pragma unroll 4
    for (int i=0;i<64;i++){
      float wv=Wl[i*128];
      a0+=Vraw[0][kg*64+i]*wv; a1+=Vraw[1][kg*64+i]*wv;
      a2+=Vraw[2][kg*64+i]*wv; a3+=Vraw[3][kg*64+i]*wv;
    }
    redL[tid]=a0; redL[256+tid]=a1; redL[512+tid]=a2; redL[768+tid]=a3;
  }
  __syncthreads();
  {
    float t0=redL[wid*256+lane]+redL[wid*256+128+lane]+bB1[lane];
    float t1=redL[wid*256+lane+64]+redL[wid*256+128+lane+64]+bB1[lane+64];
    float m=wsum(t0+t1)*(1.f/128.f);
    t0-=m; t1-=m;
    float ssq=wsum(t0*t0+t1*t1);
    B1v[(long)(r0+wid)*128+lane]=t0;
    B1v[(long)(r0+wid)*128+lane+64]=t1;
    if (lane==0) sb1[r0+wid]=ssq;
  }
}

// att[b][i][j][h] = 1/107 except [b][0][1..106][:] = 1/217088; one block per b
__global__ __launch_bounds__(256) void fill_att2(float4* __restrict__ att4){
  const float v1 = 1.f/107.f, v2 = 1.f/217088.f;
  long base = (long)blockIdx.x*11449;
  for (int i=threadIdx.x; i<11449; i+=256){
    float v = (i>=1 && i<107) ? v2 : v1;
    att4[base+i] = make_float4(v,v,v,v);
  }
}

extern "C" void kernel_launch(void* const* d_in, const int* in_sizes, int n_in,
                              void* d_out, int out_size, void* d_ws, size_t ws_size,
                              hipStream_t stream) {
  const float* news_emb = (const float*)d_in[0];
  const float* base_embs= (const float*)d_in[1];
  const float* ctx_w  = (const float*)d_in[2];
  const float* ctx_b  = (const float*)d_in[3];
  const float* proj_w = (const float*)d_in[4];
  const float* proj_b = (const float*)d_in[5];
  const float* fus_w  = (const float*)d_in[6];
  const float* fus_b  = (const float*)d_in[7];
  const float* enc_w  = (const float*)d_in[8];
  const float* enc_b  = (const float*)d_in[9];
  const float* enc_g  = (const float*)d_in[10];
  const float* enc_beta=(const float*)d_in[11];
  const float* lin_nw = (const float*)d_in[12];
  const float* lin_nb = (const float*)d_in[13];
  const float* lin_ng = (const float*)d_in[14];
  const float* lin_nbeta=(const float*)d_in[15];
  const float* kqv_nw = (const float*)d_in[16];
  const float* kqv_nb = (const float*)d_in[17];
  const float* out_nw = (const float*)d_in[18];
  const float* out_nb = (const float*)d_in[19];
  const float* skip_n = (const float*)d_in[20];
  const float* ln_ng  = (const float*)d_in[21];
  const float* ln_nbeta=(const float*)d_in[22];
  const float* lin_pw = (const float*)d_in[23];
  const float* lin_pb = (const float*)d_in[24];
  const float* lin_pg = (const float*)d_in[25];
  const float* lin_pbeta=(const float*)d_in[26];
  const float* kqv_pw = (const float*)d_in[27];
  const float* kqv_pb = (const float*)d_in[28];
  const float* out_pw = (const float*)d_in[29];
  const float* out_pb = (const float*)d_in[30];
  const float* skip_p = (const float*)d_in[31];
  const float* ln_pg  = (const float*)d_in[32];
  const float* ln_pbeta=(const float*)d_in[33];
  const float* a_rel  = (const float*)d_in[34];
  const float* m_rel  = (const float*)d_in[35];
  const float* p_rel  = (const float*)d_in[36];
  const float* cls_w  = (const float*)d_in[37];
  const float* cls_b  = (const float*)d_in[38];
  (void)in_sizes; (void)n_in; (void)out_size; (void)d_ws; (void)ws_size;

  float* out = (float*)d_out;
  float* S = out + 4096;            // att region as scratch; constant-filled last
  float* xn_enc = S + 0;            // 2048*128
  float* Vv     = S + 262144;       // 2048*128
  float* B1v    = S + 524288;       // 2048*128
  float* sb1    = S + 786432;       // 2048
  float* Ub     = S + 788480;       // 106*128
  float* A1     = S + 802048;       // 106*128
  float* sa1    = S + 815616;       // 106 (pad 128)
  float* WvC    = S + 815744;       // 2*512*32
  float* bv2    = S + 848512;       // 2*128
  float* Wnv    = S + 848768;       // 128*128
  float* bnv    = S + 865152;       // 128
  float* Wcomb  = S + 865280;       // 2*128*512
  float* bcomb  = S + 996352;       // 2*512
  float* bVb    = S + 997376;       // 128
  float* bB1    = S + 997504;       // 128

  dim3 blk(256);
  prep0<<<136,blk,0,stream>>>(ctx_w,ctx_b,proj_w,proj_b,base_embs,
      fus_w,fus_b,lin_pw,lin_pb,kqv_nw,kqv_nb,kqv_pw,kqv_pb,a_rel,m_rel,p_rel,
      Wcomb,bcomb,WvC,bv2,Wnv,bnv,bVb,bB1,Ub,A1,sa1);
  prep1<<<512,blk,0,stream>>>(news_emb,enc_w,ctx_w,fus_w,lin_pw,
      enc_b,enc_g,enc_beta,bVb,bB1,xn_enc,Vv,B1v,sb1);
  mega<<<512,blk,0,stream>>>(xn_enc,Vv,B1v,sb1,Ub,A1,sa1,Wcomb,bcomb,WvC,bv2,Wnv,bnv,
      lin_nw,lin_nb,lin_ng,lin_nbeta,lin_pg,lin_pbeta,ln_pg,ln_pbeta,
      out_nw,out_nb,out_pw,out_pb,skip_n,skip_p,ln_ng,ln_nbeta,cls_w,cls_b,out);
  fill_att2<<<2048,blk,0,stream>>>(reinterpret_cast<float4*>(S));
}

// Round 6
// 475.035 us; speedup vs baseline: 2.3444x; 1.0590x over previous
//
#include <hip/hip_runtime.h>
#include <math.h>

// B=2048, C=128, H=4, L=2, P=106, D=32
// 4 launches: PREP0 (weight folds + pred chain), PREP1 (news K=1024 pass),
// MEGA (512 thr, NB=4 b's, 2 waves per b: p-split attention + K-split gemvs,
//       att output fill fused into tail for b>=24), FILL_HEAD (b<24 att).

#define DEVFN __device__ __forceinline__

DEVFN float wsum(float v){
#pragma unroll
  for (int o=32;o;o>>=1) v += __shfl_xor(v,o);
  return v;
}
DEVFN float wmaxr(float v){
#pragma unroll
  for (int o=32;o;o>>=1) v = fmaxf(v,__shfl_xor(v,o));
  return v;
}
DEVFN float gelu_f(float x){ return 0.5f*x*(1.f+erff(x*0.70710678118654752f)); }
DEVFN float elu_f(float x){ return x>0.f?x:expm1f(x); }
DEVFN float sigm(float x){ return 1.f/(1.f+expf(-x)); }

// ---- block-wide NB=4 helpers, 512 threads, K split 4 ways ----
// outs[r*128+j] = sum_k xs[r*128+k]*W[k*128+j] + bias[j]
DEVFN void gemv128x4b(const float* __restrict__ W, const float* __restrict__ bias,
    const float* xs, float* outs, float* redL, int tid){
  __syncthreads();
  const int j=tid&127, kg=tid>>7;          // kg 0..3 -> 32 k's each
  const float* Wp = W + (kg*32)*128 + j;
  float a0=0.f,a1=0.f,a2=0.f,a3=0.f;
#pragma unroll 4
  for (int k=0;k<32;k++){
    float wv=Wp[k*128];
    a0+=xs[kg*32+k]*wv;     a1+=xs[128+kg*32+k]*wv;
    a2+=xs[256+kg*32+k]*wv; a3+=xs[384+kg*32+k]*wv;
  }
  redL[kg*512+  0+j]=a0; redL[kg*512+128+j]=a1;
  redL[kg*512+256+j]=a2; redL[kg*512+384+j]=a3;
  __syncthreads();
  { int r=tid>>7, jj=tid&127;
    outs[tid]=redL[r*128+jj]+redL[512+r*128+jj]+redL[1024+r*128+jj]+redL[1536+r*128+jj]+bias[jj]; }
  __syncthreads();
}

// us[r*512 + {j,j+256}] = xs[r] @ W[128][512] + bias, K split 2 ways
DEVFN void gemv512x4b(const float* __restrict__ W, const float* __restrict__ bias,
    const float* xs, float* us, float* redL, int tid){
  __syncthreads();
  const int j=tid&255, kg=tid>>8;          // kg 0..1 -> 64 k's each
  const float* Wp = W + (kg*64)*512;
  float a0=0,a1=0,a2=0,a3=0,a4=0,a5=0,a6=0,a7=0;
#pragma unroll 2
  for (int k=0;k<64;k++){
    float w0=Wp[k*512+j], w1=Wp[k*512+256+j];
    float v0=xs[kg*64+k], v1=xs[128+kg*64+k], v2=xs[256+kg*64+k], v3=xs[384+kg*64+k];
    a0+=v0*w0; a1+=v0*w1; a2+=v1*w0; a3+=v1*w1;
    a4+=v2*w0; a5+=v2*w1; a6+=v3*w0; a7+=v3*w1;
  }
  redL[kg*2048+0*512    +j]=a0; redL[kg*2048+0*512+256+j]=a1;
  redL[kg*2048+1*512    +j]=a2; redL[kg*2048+1*512+256+j]=a3;
  redL[kg*2048+2*512    +j]=a4; redL[kg*2048+2*512+256+j]=a5;
  redL[kg*2048+3*512    +j]=a6; redL[kg*2048+3*512+256+j]=a7;
  __syncthreads();
  for (int idx=tid; idx<2048; idx+=512)
    us[idx]=redL[idx]+redL[2048+idx]+bias[idx&511];
  __syncthreads();
}

// outs[r*128 + j] = sum_cc Ys[r*512 + h*128+cc]*WvC[(h*128+cc)*32+d] + bv[j], j=(h*32+d)
DEVFN void aggvx4b(const float* __restrict__ WvC, const float* __restrict__ bv,
    const float* Ys, float* outs, float* redL, int tid){
  __syncthreads();
  const int j=tid&127, kg=tid>>7;
  const int h=j>>5, d=j&31;
  const float* Wp = WvC + (h*128 + kg*32)*32 + d;
  const float* y0 = Ys + h*128 + kg*32;
  float a0=0,a1=0,a2=0,a3=0;
#pragma unroll 4
  for (int i=0;i<32;i++){
    float wv=Wp[i*32];
    a0+=y0[i]*wv; a1+=y0[512+i]*wv; a2+=y0[1024+i]*wv; a3+=y0[1536+i]*wv;
  }
  redL[kg*512+  0+j]=a0; redL[kg*512+128+j]=a1;
  redL[kg*512+256+j]=a2; redL[kg*512+384+j]=a3;
  __syncthreads();
  { int r=tid>>7, jj=tid&127;
    outs[tid]=redL[r*128+jj]+redL[512+r*128+jj]+redL[1024+r*128+jj]+redL[1536+r*128+jj]+bv[jj]; }
  __syncthreads();
}

// out = elu(LN(sn*A + (1-sn)*Bx + R; g,be))  -- per-wave, no barriers
DEVFN void rowmode2w(const float* A, const float* Bx, const float* R,
  const float* __restrict__ g, const float* __restrict__ be, float skipval,
  float* outr, int lane){
  float sn=sigm(skipval), os=1.f-sn;
  float t0=sn*A[lane]+os*Bx[lane]+R[lane];
  float t1=sn*A[lane+64]+os*Bx[lane+64]+R[lane+64];
  float m=wsum(t0+t1)*(1.f/128.f);
  float d0=t0-m,d1=t1-m;
  float var=wsum(d0*d0+d1*d1)*(1.f/128.f);
  float inv=rsqrtf(var+1e-5f);
  outr[lane]=elu_f(d0*inv*g[lane]+be[lane]);
  outr[lane+64]=elu_f(d1*inv*g[lane+64]+be[lane+64]);
}

__global__ __launch_bounds__(512,4) void mega(
  const float* __restrict__ xn_enc_g, const float* __restrict__ Vv_g,
  const float* __restrict__ B1v_g, const float* __restrict__ sb1_g,
  const float* __restrict__ Ub, const float* __restrict__ A1, const float* __restrict__ sa1,
  const float* __restrict__ Wcomb, const float* __restrict__ bcomb,
  const float* __restrict__ WvC, const float* __restrict__ bv2,
  const float* __restrict__ Wnv, const float* __restrict__ bnv,
  const float* __restrict__ lin_nw, const float* __restrict__ lin_nb,
  const float* __restrict__ lin_ng, const float* __restrict__ lin_nbeta,
  const float* __restrict__ lin_pg, const float* __restrict__ lin_pbeta,
  const float* __restrict__ ln_pg, const float* __restrict__ ln_pbeta,
  const float* __restrict__ out_nw, const float* __restrict__ out_nb,
  const float* __restrict__ out_pw, const float* __restrict__ out_pb,
  const float* __restrict__ skip_n, const float* __restrict__ skip_p,
  const float* __restrict__ ln_ng, const float* __restrict__ ln_nbeta,
  const float* __restrict__ cls_w, const float* __restrict__ cls_b,
  float* __restrict__ out)
{
  __shared__ float xe[512], x1[512], xA[512], W0s[512], Bv[512], Vvs[512];
  __shared__ float scratch[2048];     // us then Ys, per-b 512
  __shared__ float ss[2048];          // scores -> alpha, per-b [h][128]
  __shared__ float redL[4096];        // partial pool
  __shared__ float rowa[512], rowb[512];
  __shared__ float inv0[512], m1s[512], i1s[512];
  __shared__ float gAs[128], bAs[128], g0s[128], b0s[128];
  const int tid=threadIdx.x, lane=tid&63, wave=tid>>6, w2=wave>>1, half=wave&1;
  const int bbase=blockIdx.x*4, b=bbase+w2;
  // stage (512 = 4b x 128 exactly)
  xe[tid]=xn_enc_g[(long)bbase*128+tid];
  Bv[tid]=B1v_g[(long)bbase*128+tid];
  Vvs[tid]=Vv_g[(long)bbase*128+tid];
  if (tid<128){ gAs[tid]=lin_pg[tid]; bAs[tid]=lin_pbeta[tid]; g0s[tid]=ln_pg[tid]; b0s[tid]=ln_pbeta[tid]; }
  // linn = xe@lin_nw + lin_nb (entry sync covers stage)
  gemv128x4b(lin_nw, lin_nb, xe, rowa, redL, tid);
  if (half==0){ // x1 = LN(rowa)+xe for b-slot w2
    const float* rw=rowa+w2*128;
    float t0=rw[lane], t1=rw[lane+64];
    float m=wsum(t0+t1)*(1.f/128.f);
    float d0=t0-m,d1=t1-m;
    float var=wsum(d0*d0+d1*d1)*(1.f/128.f);
    float inv=rsqrtf(var+1e-5f);
    x1[w2*128+lane]   =d0*inv*lin_ng[lane]   +lin_nbeta[lane]   +xe[w2*128+lane];
    x1[w2*128+lane+64]=d1*inv*lin_ng[lane+64]+lin_nbeta[lane+64]+xe[w2*128+lane+64];
  }
  gemv512x4b(Wcomb, bcomb, x1, scratch, redL, tid);
  // pointers (LDS, per b-slot)
  const float2* A12=(const float2*)A1;
  const float2* Ub2=(const float2*)Ub;
  const float2* BvW=(const float2*)(Bv+w2*128);
  const float2* VvW=(const float2*)(Vvs+w2*128);
  const float2* gAW=(const float2*)gAs;
  const float2* bAW=(const float2*)bAs;
  const float2* g0W=(const float2*)g0s;
  const float2* b0W=(const float2*)b0s;
  const float2* UsW=(const float2*)(scratch+w2*512);
  const float sb = sb1_g[b];
  const int p = half*64 + lane;     // one p per lane across the wave pair
  const bool act = (p<106);
  // ======== layer 0 pass A ========
  if (act){
    float dt=0.f;
#pragma unroll 4
    for (int c=0;c<64;c++){
      float2 a=A12[p*64+c], bbv=BvW[c];
      dt += a.x*bbv.x + a.y*bbv.y;
    }
    float iv = rsqrtf((sa1[p]+2.f*dt+sb)*(1.f/128.f)+1e-5f);
    inv0[w2*128+p]=iv;
    float s0=0,s1=0,s2=0,s3=0;
#pragma unroll 2
    for (int c=0;c<64;c++){
      float2 a=A12[p*64+c], u=Ub2[p*64+c];
      float2 bbv=BvW[c], vv=VvW[c], ga=gAW[c], ba=bAW[c];
      float2 q0=UsW[c], q1=UsW[64+c], q2=UsW[128+c], q3=UsW[192+c];
      float rx=(a.x+bbv.x)*iv*ga.x+ba.x+u.x+vv.x;
      float ry=(a.y+bbv.y)*iv*ga.y+ba.y+u.y+vv.y;
      s0+=rx*q0.x+ry*q0.y; s1+=rx*q1.x+ry*q1.y;
      s2+=rx*q2.x+ry*q2.y; s3+=rx*q3.x+ry*q3.y;
    }
    ss[w2*512+  0+p]=s0; ss[w2*512+128+p]=s1;
    ss[w2*512+256+p]=s2; ss[w2*512+384+p]=s3;
  }
  __syncthreads();
  // softmax: 16 jobs (4b x 4h), 2 per wave
#pragma unroll
  for (int k=0;k<2;k++){
    int jj=wave*2+k, jb=jj>>2, jh=jj&3;
    float* row = ss + jb*512 + jh*128;
    float v1=(lane<106)? row[lane] : -1e30f;
    float v2=(lane+64<106)? row[lane+64] : -1e30f;
    float mx=wmaxr(fmaxf(v1,v2));
    float e1=(lane<106)? expf(v1-mx):0.f;
    float e2=(lane+64<106)? expf(v2-mx):0.f;
    float den=wsum(e1+e2);
    float rinv=1.f/den;
    if (lane<106) row[lane]=e1*rinv;
    if (lane+64<106) row[lane+64]=e2*rinv;
  }
  __syncthreads();
  // ======== layer 0 pass B (p range split across wave pair) ========
  {
    const float2 bbv=BvW[lane], vv=VvW[lane], ga=gAW[lane], ba=bAW[lane];
    float2 y0={0,0},y1={0,0},y2={0,0},y3={0,0};
    const float* al = ss + w2*512;
    const float* ivp = inv0 + w2*128;
    const int pst=half*53, pen=pst+53;
    for (int pp=pst; pp<pen; pp++){
      float2 a=A12[pp*64+lane], u=Ub2[pp*64+lane];
      float ivv=ivp[pp];
      float rx=(a.x+bbv.x)*ivv*ga.x+ba.x+u.x+vv.x;
      float ry=(a.y+bbv.y)*ivv*ga.y+ba.y+u.y+vv.y;
      float a0=al[pp],a1=al[128+pp],a2=al[256+pp],a3=al[384+pp];
      y0.x+=a0*rx; y0.y+=a0*ry; y1.x+=a1*rx; y1.y+=a1*ry;
      y2.x+=a2*rx; y2.y+=a2*ry; y3.x+=a3*rx; y3.y+=a3*ry;
    }
    float2* rw=(float2*)(redL + half*2048 + w2*512);
    rw[lane]=y0; rw[64+lane]=y1; rw[128+lane]=y2; rw[192+lane]=y3;
  }
  __syncthreads();
  for (int idx=tid; idx<2048; idx+=512) scratch[idx]=redL[idx]+redL[2048+idx];
  aggvx4b(WvC, bv2, scratch, rowa, redL, tid);
  rowb[tid]=gelu_f(rowa[tid]);
  gemv128x4b(out_nw, out_nb, rowb, rowa, redL, tid);
  if (half==0)
    rowmode2w(rowa+w2*128, x1+w2*128, xe+w2*128, ln_ng, ln_nbeta, skip_n[0], xA+w2*128, lane);
  // pred-side layer-0 output row
  gemv128x4b(Wnv, bnv, x1, rowa, redL, tid);
  rowb[tid]=gelu_f(rowa[tid]);
  gemv128x4b(out_pw, out_pb, rowb, W0s, redL, tid);
  // ======== layer 1 ========
  gemv512x4b(Wcomb+65536, bcomb+512, xA, scratch, redL, tid);
  const float sp0=sigm(skip_p[0]), omsp=1.f-sp0;
  const float2* W0W=(const float2*)(W0s+w2*128);
  if (act){
    float iv = inv0[w2*128+p];
    float st=0.f, sq=0.f;
#pragma unroll 2
    for (int c=0;c<64;c++){
      float2 a=A12[p*64+c], u=Ub2[p*64+c];
      float2 bbv=BvW[c], vv=VvW[c], ga=gAW[c], ba=bAW[c], w0=W0W[c];
      float rx=(a.x+bbv.x)*iv*ga.x+ba.x+u.x+vv.x;
      float ry=(a.y+bbv.y)*iv*ga.y+ba.y+u.y+vv.y;
      float t0=sp0*w0.x+omsp*rx+u.x+vv.x;
      float t1=sp0*w0.y+omsp*ry+u.y+vv.y;
      st+=t0+t1; sq+=t0*t0+t1*t1;
    }
    float mA=st*(1.f/128.f);
    float ivA=rsqrtf(fmaxf(sq*(1.f/128.f)-mA*mA,0.f)+1e-5f);
    m1s[w2*128+p]=mA; i1s[w2*128+p]=ivA;
    float s0=0,s1=0,s2=0,s3=0;
#pragma unroll 2
    for (int c=0;c<64;c++){
      float2 a=A12[p*64+c], u=Ub2[p*64+c];
      float2 bbv=BvW[c], vv=VvW[c], ga=gAW[c], ba=bAW[c], w0=W0W[c];
      float2 g0=g0W[c], b0v=b0W[c];
      float2 q0=UsW[c], q1=UsW[64+c], q2=UsW[128+c], q3=UsW[192+c];
      float rx=(a.x+bbv.x)*iv*ga.x+ba.x+u.x+vv.x;
      float ry=(a.y+bbv.y)*iv*ga.y+ba.y+u.y+vv.y;
      float t0=sp0*w0.x+omsp*rx+u.x+vv.x;
      float t1=sp0*w0.y+omsp*ry+u.y+vv.y;
      float r0=elu_f((t0-mA)*ivA*g0.x+b0v.x);
      float r1=elu_f((t1-mA)*ivA*g0.y+b0v.y);
      s0+=r0*q0.x+r1*q0.y; s1+=r0*q1.x+r1*q1.y;
      s2+=r0*q2.x+r1*q2.y; s3+=r0*q3.x+r1*q3.y;
    }
    ss[w2*512+  0+p]=s0; ss[w2*512+128+p]=s1;
    ss[w2*512+256+p]=s2; ss[w2*512+384+p]=s3;
  }
  __syncthreads();
#pragma unroll
  for (int k=0;k<2;k++){
    int jj=wave*2+k, jb=jj>>2, jh=jj&3;
    float* row = ss + jb*512 + jh*128;
    float v1=(lane<106)? row[lane] : -1e30f;
    float v2=(lane+64<106)? row[lane+64] : -1e30f;
    float mx=wmaxr(fmaxf(v1,v2));
    float e1=(lane<106)? expf(v1-mx):0.f;
    float e2=(lane+64<106)? expf(v2-mx):0.f;
    float den=wsum(e1+e2);
    float rinv=1.f/den;
    if (lane<106) row[lane]=e1*rinv;
    if (lane+64<106) row[lane+64]=e2*rinv;
  }
  __syncthreads();
  { // pass B layer 1
    const float2 bbv=BvW[lane], vv=VvW[lane], ga=gAW[lane], ba=bAW[lane];
    const float2 w0=W0W[lane], g0=g0W[lane], b0v=b0W[lane];
    float2 y0={0,0},y1={0,0},y2={0,0},y3={0,0};
    const float* al = ss + w2*512;
    const float* ivp = inv0 + w2*128;
    const float* mp = m1s + w2*128;
    const float* ip = i1s + w2*128;
    const int pst=half*53, pen=pst+53;
    for (int pp=pst; pp<pen; pp++){
      float2 a=A12[pp*64+lane], u=Ub2[pp*64+lane];
      float ivv=ivp[pp], m=mp[pp], i2=ip[pp];
      float rx=(a.x+bbv.x)*ivv*ga.x+ba.x+u.x+vv.x;
      float ry=(a.y+bbv.y)*ivv*ga.y+ba.y+u.y+vv.y;
      float tx=sp0*w0.x+omsp*rx+u.x+vv.x;
      float ty=sp0*w0.y+omsp*ry+u.y+vv.y;
      float r0=elu_f((tx-m)*i2*g0.x+b0v.x);
      float r1=elu_f((ty-m)*i2*g0.y+b0v.y);
      float a0=al[pp],a1=al[128+pp],a2=al[256+pp],a3=al[384+pp];
      y0.x+=a0*r0; y0.y+=a0*r1; y1.x+=a1*r0; y1.y+=a1*r1;
      y2.x+=a2*r0; y2.y+=a2*r1; y3.x+=a3*r0; y3.y+=a3*r1;
    }
    float2* rw=(float2*)(redL + half*2048 + w2*512);
    rw[lane]=y0; rw[64+lane]=y1; rw[128+lane]=y2; rw[192+lane]=y3;
  }
  __syncthreads();
  for (int idx=tid; idx<2048; idx+=512) scratch[idx]=redL[idx]+redL[2048+idx];
  aggvx4b(WvC+16384, bv2+128, scratch, rowa, redL, tid);
  rowb[tid]=gelu_f(rowa[tid]);
  gemv128x4b(out_nw+16384, out_nb+128, rowb, rowa, redL, tid);
  if (half==0){
    rowmode2w(rowa+w2*128, xA+w2*128, xA+w2*128, ln_ng+128, ln_nbeta+128, skip_n[1], rowb+w2*128, lane);
    // logits (reads rowb written by this same wave)
    float xv0=rowb[w2*128+lane], xv1=rowb[w2*128+lane+64];
    float a0=xv0*cls_w[lane*2]  +xv1*cls_w[(lane+64)*2];
    float a1=xv0*cls_w[lane*2+1]+xv1*cls_w[(lane+64)*2+1];
    a0=wsum(a0); a1=wsum(a1);
    if (lane==0){ out[b*2]=a0+cls_b[0]; out[b*2+1]=a1+cls_b[1]; }
  }
  // fused att fill for this block's 4 b's (skip b<24: that region is scratch)
  if (bbase >= 24){
    float4* att4 = reinterpret_cast<float4*>(out + 4096);
    const float va=1.f/107.f, vb=1.f/217088.f;
#pragma unroll
    for (int r=0;r<4;r++){
      long base=(long)(bbase+r)*11449;
      for (int i=tid;i<11449;i+=512){
        float v=(i>=1 && i<107)? vb : va;
        att4[base+i]=make_float4(v,v,v,v);
      }
    }
  }
}

__global__ __launch_bounds__(256) void prep0(
  const float* __restrict__ ctx_w, const float* __restrict__ ctx_b,
  const float* __restrict__ proj_w, const float* __restrict__ proj_b,
  const float* __restrict__ base_embs,
  const float* __restrict__ fus_w, const float* __restrict__ fus_b,
  const float* __restrict__ lin_pw, const float* __restrict__ lin_pb,
  const float* __restrict__ kqv_nw, const float* __restrict__ kqv_nb,
  const float* __restrict__ kqv_pw, const float* __restrict__ kqv_pb,
  const float* __restrict__ a_rel, const float* __restrict__ m_rel,
  const float* __restrict__ p_rel,
  float* __restrict__ Wcomb, float* __restrict__ bcomb,
  float* __restrict__ WvC, float* __restrict__ bv2,
  float* __restrict__ Wnv, float* __restrict__ bnv,
  float* __restrict__ bVb, float* __restrict__ bB1,
  float* __restrict__ Ub, float* __restrict__ A1, float* __restrict__ sa1)
{
  const int blk=blockIdx.x, tid=threadIdx.x, lane=tid&63, wid=tid>>6;
  __shared__ float sh[2048];
  __shared__ float row1[128], row2[128], row3[128];
  __shared__ float red[256];
  if (blk < 16){
    int l=blk>>3, jq=blk&7, h=jq>>1, cc0=(jq&1)*64;
    float* wk = sh;
    float ps = p_rel[(l*2+1)*4+h]*0.17677669529663687f;
    for (int idx=tid; idx<2048; idx+=256){
      int e=idx>>6, cl=idx&63;
      float acc=0.f;
#pragma unroll
      for (int d=0;d<32;d++)
        acc += kqv_pw[(long)l*49152 + (cc0+cl)*384 + h*32 + d]
             * a_rel[((l*2+1)*4+h)*1024 + d*32 + e];
      wk[e*64+cl]=acc*ps;
    }
    __syncthreads();
    for (int idx=tid; idx<8192; idx+=256){
      int c=idx>>6, jl=idx&63;
      float acc=0.f;
#pragma unroll
      for (int e=0;e<32;e++) acc += kqv_nw[(long)l*49152 + c*384 + 128 + h*32 + e]*wk[e*64+jl];
      Wcomb[(long)l*65536 + c*512 + h*128 + cc0 + jl]=acc;
    }
    if (tid<64){
      float acc=0.f;
#pragma unroll
      for (int e=0;e<32;e++) acc += kqv_nb[l*384 + 128 + h*32 + e]*wk[e*64+tid];
      bcomb[l*512 + h*128 + cc0 + tid]=acc;
    }
  } else if (blk < 24){
    int t=blk-16, l=t>>2, h=t&3;
    float* rl = sh;
    for (int i=tid;i<1024;i+=256) rl[i]=m_rel[((l*2+1)*4+h)*1024+i];
    __syncthreads();
    for (int idx=tid; idx<4096; idx+=256){
      int cc=idx>>5, d=idx&31;
      float acc=0.f;
#pragma unroll
      for (int dp=0;dp<32;dp++) acc += kqv_pw[(long)l*49152 + cc*384 + 256 + h*32 + dp]*rl[dp*32+d];
      WvC[l*16384 + (h*128+cc)*32 + d]=acc;
    }
  } else if (blk==24){
    {
      int l=tid>>7, j=tid&127, h=(j>>5)&3, d=j&31;
      float acc=0.f;
#pragma unroll
      for (int dp=0;dp<32;dp++) acc += kqv_pb[l*384+256+h*32+dp]*m_rel[((l*2+1)*4+h)*1024+dp*32+d];
      bv2[l*128+j]=acc;
    }
    if (tid < 128){
      int j=tid, h=j>>5, d=j&31;
      float acc=0.f;
#pragma unroll
      for (int dp=0;dp<32;dp++) acc += kqv_nb[256+h*32+dp]*m_rel[h*1024+dp*32+d];
      bnv[j]=acc;
    }
  } else if (blk < 29){
    int h=blk-25;
    float* rl=sh;
    for (int i=tid;i<1024;i+=256) rl[i]=m_rel[h*1024+i];
    __syncthreads();
    for (int idx=tid; idx<4096; idx+=256){
      int c=idx>>5, d=idx&31;
      float acc=0.f;
#pragma unroll
      for (int dp=0;dp<32;dp++) acc += kqv_nw[c*384+256+h*32+dp]*rl[dp*32+d];
      Wnv[c*128 + h*32 + d]=acc;
    }
  } else if (blk==29){
    int j=tid&127, kg=tid>>7;
    float acc=0.f;
#pragma unroll 4
    for (int i=0;i<64;i++) acc += ctx_b[kg*64+i]*fus_w[(128+kg*64+i)*128+j];
    red[tid]=acc; __syncthreads();
    if (tid<128){ float v=red[tid]+red[tid+128]; bVb[tid]=v; row1[tid]=v; }
    __syncthreads();
    acc=0.f;
#pragma unroll 4
    for (int i=0;i<64;i++) acc += row1[kg*64+i]*lin_pw[(kg*64+i)*128+j];
    red[tid]=acc; __syncthreads();
    if (tid<128) bB1[tid]=red[tid]+red[tid+128]+lin_pb[tid];
  } else {
    // pred chain, one block per p
    int p = blk-30;
    float* xs1=sh;
    int j=tid&127, kg=tid>>7;
    for (int i=tid;i<1024;i+=256) xs1[i]=base_embs[(long)p*1024+i];
    __syncthreads();
    float acc=0.f;
#pragma unroll 4
    for (int k=0;k<512;k++) acc += xs1[kg*512+k]*proj_w[(long)(kg*512+k)*128+j];
    red[tid]=acc; __syncthreads();
    if (tid<128) row1[tid]=red[tid]+red[tid+128]+proj_b[tid];
    __syncthreads();
    acc=0.f;
#pragma unroll 4
    for (int i=0;i<64;i++) acc += row1[kg*64+i]*fus_w[(long)(kg*64+i)*128+j];
    red[tid]=acc; __syncthreads();
    if (tid<128){ float v=red[tid]+red[tid+128]+fus_b[tid]; row2[tid]=v; Ub[(long)p*128+tid]=v; }
    __syncthreads();
    acc=0.f;
#pragma unroll 4
    for (int i=0;i<64;i++) acc += row2[kg*64+i]*lin_pw[(long)(kg*64+i)*128+j];
    red[tid]=acc; __syncthreads();
    if (tid<128) row3[tid]=red[tid]+red[tid+128];
    __syncthreads();
    if (wid==0){
      float t0=row3[lane], t1=row3[lane+64];
      float m=wsum(t0+t1)*(1.f/128.f);
      t0-=m; t1-=m;
      float ssq=wsum(t0*t0+t1*t1);
      A1[(long)p*128+lane]=t0; A1[(long)p*128+lane+64]=t1;
      if (lane==0) sa1[p]=ssq;
    }
  }
}

__global__ __launch_bounds__(256) void prep1(
  const float* __restrict__ news_emb,
  const float* __restrict__ enc_w, const float* __restrict__ ctx_w,
  const float* __restrict__ fus_w, const float* __restrict__ lin_pw,
  const float* __restrict__ enc_b, const float* __restrict__ enc_g, const float* __restrict__ enc_beta,
  const float* __restrict__ bVb, const float* __restrict__ bB1,
  float* __restrict__ xn_enc, float* __restrict__ Vv, float* __restrict__ B1v, float* __restrict__ sb1)
{
  __shared__ __align__(16) float xs[4][1024];
  __shared__ float redL[1024];
  __shared__ float rowsC[4][128];
  __shared__ float Vraw[4][128];
  const int r0=blockIdx.x*4, tid=threadIdx.x, lane=tid&63, wid=tid>>6;
  for (int r=0;r<4;r++){
    float4 v=*(const float4*)(news_emb+(long)(r0+r)*1024+tid*4);
    *(float4*)(&xs[r][tid*4])=v;
  }
  __syncthreads();
  const int j=tid&127, kg=tid>>7;
  float ae0=0,ae1=0,ae2=0,ae3=0, ac0=0,ac1=0,ac2=0,ac3=0;
  {
    const float* We=enc_w+(long)(kg*512)*128+j;
    const float* Wc=ctx_w+(long)(kg*512)*128+j;
#pragma unroll 2
    for (int k=0;k<512;k++){
      float we=We[(long)k*128], wc=Wc[(long)k*128];
      float v0=xs[0][kg*512+k], v1=xs[1][kg*512+k], v2=xs[2][kg*512+k], v3=xs[3][kg*512+k];
      ae0+=v0*we; ae1+=v1*we; ae2+=v2*we; ae3+=v3*we;
      ac0+=v0*wc; ac1+=v1*wc; ac2+=v2*wc; ac3+=v3*wc;
    }
  }
  redL[tid]=ae0; redL[256+tid]=ae1; redL[512+tid]=ae2; redL[768+tid]=ae3;
  __syncthreads();
  {
    float t0=redL[wid*256+lane]+redL[wid*256+128+lane]+enc_b[lane];
    float t1=redL[wid*256+lane+64]+redL[wid*256+128+lane+64]+enc_b[lane+64];
    float m=wsum(t0+t1)*(1.f/128.f);
    float d0=t0-m,d1=t1-m;
    float var=wsum(d0*d0+d1*d1)*(1.f/128.f);
    float inv=rsqrtf(var+1e-5f);
    xn_enc[(long)(r0+wid)*128+lane]   =elu_f(d0*inv*enc_g[lane]   +enc_beta[lane]);
    xn_enc[(long)(r0+wid)*128+lane+64]=elu_f(d1*inv*enc_g[lane+64]+enc_beta[lane+64]);
  }
  __syncthreads();
  redL[tid]=ac0; redL[256+tid]=ac1; redL[512+tid]=ac2; redL[768+tid]=ac3;
  __syncthreads();
  for (int i=tid;i<512;i+=256){
    int r=i>>7,jj=i&127;
    rowsC[r][jj]=redL[r*256+jj]+redL[r*256+128+jj];
  }
  __syncthreads();
  {
    const float* Wf=fus_w+(128+kg*64)*128+j;
    float a0=0,a1=0,a2=0,a3=0;
#pragma unroll 4
    for (int i=0;i<64;i++){
      float wv=Wf[i*128];
      a0+=rowsC[0][kg*64+i]*wv; a1+=rowsC[1][kg*64+i]*wv;
      a2+=rowsC[2][kg*64+i]*wv; a3+=rowsC[3][kg*64+i]*wv;
    }
    redL[tid]=a0; redL[256+tid]=a1; redL[512+tid]=a2; redL[768+tid]=a3;
  }
  __syncthreads();
  for (int i=tid;i<512;i+=256){
    int r=i>>7,jj=i&127;
    float v=redL[r*256+jj]+redL[r*256+128+jj];
    Vraw[r][jj]=v;
    Vv[(long)(r0+r)*128+jj]=v+bVb[jj];
  }
  __syncthreads();
  {
    const float* Wl=lin_pw+(kg*64)*128+j;
    float a0=0,a1=0,a2=0,a3=0;
#pragma unroll 4
    for (int i=0;i<64;i++){
      float wv=Wl[i*128];
      a0+=Vraw[0][kg*64+i]*wv; a1+=Vraw[1][kg*64+i]*wv;
      a2+=Vraw[2][kg*64+i]*wv; a3+=Vraw[3][kg*64+i]*wv;
    }
    redL[tid]=a0; redL[256+tid]=a1; redL[512+tid]=a2; redL[768+tid]=a3;
  }
  __syncthreads();
  {
    float t0=redL[wid*256+lane]+redL[wid*256+128+lane]+bB1[lane];
    float t1=redL[wid*256+lane+64]+redL[wid*256+128+lane+64]+bB1[lane+64];
    float m=wsum(t0+t1)*(1.f/128.f);
    t0-=m; t1-=m;
    float ssq=wsum(t0*t0+t1*t1);
    B1v[(long)(r0+wid)*128+lane]=t0;
    B1v[(long)(r0+wid)*128+lane+64]=t1;
    if (lane==0) sb1[r0+wid]=ssq;
  }
}

// head-fill: att for b < 24 (scratch zone) after mega
__global__ __launch_bounds__(256) void fill_att2(float4* __restrict__ att4){
  const float v1 = 1.f/107.f, v2 = 1.f/217088.f;
  long base = (long)blockIdx.x*11449;
  for (int i=threadIdx.x; i<11449; i+=256){
    float v = (i>=1 && i<107) ? v2 : v1;
    att4[base+i] = make_float4(v,v,v,v);
  }
}

extern "C" void kernel_launch(void* const* d_in, const int* in_sizes, int n_in,
                              void* d_out, int out_size, void* d_ws, size_t ws_size,
                              hipStream_t stream) {
  const float* news_emb = (const float*)d_in[0];
  const float* base_embs= (const float*)d_in[1];
  const float* ctx_w  = (const float*)d_in[2];
  const float* ctx_b  = (const float*)d_in[3];
  const float* proj_w = (const float*)d_in[4];
  const float* proj_b = (const float*)d_in[5];
  const float* fus_w  = (const float*)d_in[6];
  const float* fus_b  = (const float*)d_in[7];
  const float* enc_w  = (const float*)d_in[8];
  const float* enc_b  = (const float*)d_in[9];
  const float* enc_g  = (const float*)d_in[10];
  const float* enc_beta=(const float*)d_in[11];
  const float* lin_nw = (const float*)d_in[12];
  const float* lin_nb = (const float*)d_in[13];
  const float* lin_ng = (const float*)d_in[14];
  const float* lin_nbeta=(const float*)d_in[15];
  const float* kqv_nw = (const float*)d_in[16];
  const float* kqv_nb = (const float*)d_in[17];
  const float* out_nw = (const float*)d_in[18];
  const float* out_nb = (const float*)d_in[19];
  const float* skip_n = (const float*)d_in[20];
  const float* ln_ng  = (const float*)d_in[21];
  const float* ln_nbeta=(const float*)d_in[22];
  const float* lin_pw = (const float*)d_in[23];
  const float* lin_pb = (const float*)d_in[24];
  const float* lin_pg = (const float*)d_in[25];
  const float* lin_pbeta=(const float*)d_in[26];
  const float* kqv_pw = (const float*)d_in[27];
  const float* kqv_pb = (const float*)d_in[28];
  const float* out_pw = (const float*)d_in[29];
  const float* out_pb = (const float*)d_in[30];
  const float* skip_p = (const float*)d_in[31];
  const float* ln_pg  = (const float*)d_in[32];
  const float* ln_pbeta=(const float*)d_in[33];
  const float* a_rel  = (const float*)d_in[34];
  const float* m_rel  = (const float*)d_in[35];
  const float* p_rel  = (const float*)d_in[36];
  const float* cls_w  = (const float*)d_in[37];
  const float* cls_b  = (const float*)d_in[38];
  (void)in_sizes; (void)n_in; (void)out_size; (void)d_ws; (void)ws_size;

  float* out = (float*)d_out;
  float* S = out + 4096;            // att region as scratch (b<24 zone); head-filled last
  float* xn_enc = S + 0;            // 2048*128
  float* Vv     = S + 262144;       // 2048*128
  float* B1v    = S + 524288;       // 2048*128
  float* sb1    = S + 786432;       // 2048
  float* Ub     = S + 788480;       // 106*128
  float* A1     = S + 802048;       // 106*128
  float* sa1    = S + 815616;       // 106 (pad 128)
  float* WvC    = S + 815744;       // 2*512*32
  float* bv2    = S + 848512;       // 2*128
  float* Wnv    = S + 848768;       // 128*128
  float* bnv    = S + 865152;       // 128
  float* Wcomb  = S + 865280;       // 2*128*512
  float* bcomb  = S + 996352;       // 2*512
  float* bVb    = S + 997376;       // 128
  float* bB1    = S + 997504;       // 128

  dim3 blk(256), blkL(512);
  prep0<<<136,blk,0,stream>>>(ctx_w,ctx_b,proj_w,proj_b,base_embs,
      fus_w,fus_b,lin_pw,lin_pb,kqv_nw,kqv_nb,kqv_pw,kqv_pb,a_rel,m_rel,p_rel,
      Wcomb,bcomb,WvC,bv2,Wnv,bnv,bVb,bB1,Ub,A1,sa1);
  prep1<<<512,blk,0,stream>>>(news_emb,enc_w,ctx_w,fus_w,lin_pw,
      enc_b,enc_g,enc_beta,bVb,bB1,xn_enc,Vv,B1v,sb1);
  mega<<<512,blkL,0,stream>>>(xn_enc,Vv,B1v,sb1,Ub,A1,sa1,Wcomb,bcomb,WvC,bv2,Wnv,bnv,
      lin_nw,lin_nb,lin_ng,lin_nbeta,lin_pg,lin_pbeta,ln_pg,ln_pbeta,
      out_nw,out_nb,out_pw,out_pb,skip_n,skip_p,ln_ng,ln_nbeta,cls_w,cls_b,out);
  fill_att2<<<24,blk,0,stream>>>(reinterpret_cast<float4*>(S));
}

// Round 7
// 347.228 us; speedup vs baseline: 3.2073x; 1.3681x over previous
//
#include <hip/hip_runtime.h>
#include <math.h>

// B=2048, C=128, H=4, L=2, P=106, D=32
// 3 launches: PREP (weight folds + pred chain + news K=1024 pass, one kernel),
// MEGA (512 thr, NB=4 b's, 2 waves/b, fused-sweep attention, direct gemvs,
//       att fill interleaved across phases for b>=24), FILL_HEAD (b<24 att).

#define DEVFN __device__ __forceinline__

DEVFN float wsum(float v){
#pragma unroll
  for (int o=32;o;o>>=1) v += __shfl_xor(v,o);
  return v;
}
DEVFN float wmaxr(float v){
#pragma unroll
  for (int o=32;o;o>>=1) v = fmaxf(v,__shfl_xor(v,o));
  return v;
}
DEVFN float gelu_f(float x){ return 0.5f*x*(1.f+erff(x*0.70710678118654752f)); }
DEVFN float elu_f(float x){ return x>0.f?x:expm1f(x); }
DEVFN float sigm(float x){ return 1.f/(1.f+expf(-x)); }

// direct gemvs: one output per thread, no reductions, no internal barriers
DEVFN void dgemv128(const float* __restrict__ W, const float* __restrict__ bias,
    const float* xs, float* outs, int tid){
  const int r=tid>>7, j=tid&127;
  const float* x = xs + r*128;
  float acc = bias[j];
#pragma unroll 4
  for (int k=0;k<128;k++) acc += x[k]*W[k*128+j];
  outs[tid]=acc;
}
DEVFN void dgemv512(const float* __restrict__ W, const float* __restrict__ bias,
    const float* xs, float* us, int tid){
  float b=bias[tid];
  float a0=b,a1=b,a2=b,a3=b;
#pragma unroll 2
  for (int k=0;k<128;k++){
    float w=W[k*512+tid];
    a0+=xs[k]*w; a1+=xs[128+k]*w; a2+=xs[256+k]*w; a3+=xs[384+k]*w;
  }
  us[tid]=a0; us[512+tid]=a1; us[1024+tid]=a2; us[1536+tid]=a3;
}
DEVFN void daggv(const float* __restrict__ WvC, const float* __restrict__ bv,
    const float* Ys, float* outs, int tid){
  const int r=tid>>7, j=tid&127, h=j>>5, d=j&31;
  const float* y = Ys + r*512 + h*128;
  const float* Wp = WvC + (h*128)*32 + d;
  float acc=bv[j];
#pragma unroll 4
  for (int cc=0;cc<128;cc++) acc += y[cc]*Wp[cc*32];
  outs[tid]=acc;
}
// out = elu(LN(sn*A + (1-sn)*Bx + R; g,be)) -- per-wave
DEVFN void rowmode2w(const float* A, const float* Bx, const float* R,
  const float* __restrict__ g, const float* __restrict__ be, float skipval,
  float* outr, int lane){
  float sn=sigm(skipval), os=1.f-sn;
  float t0=sn*A[lane]+os*Bx[lane]+R[lane];
  float t1=sn*A[lane+64]+os*Bx[lane+64]+R[lane+64];
  float m=wsum(t0+t1)*(1.f/128.f);
  float d0=t0-m,d1=t1-m;
  float var=wsum(d0*d0+d1*d1)*(1.f/128.f);
  float inv=rsqrtf(var+1e-5f);
  outr[lane]=elu_f(d0*inv*g[lane]+be[lane]);
  outr[lane+64]=elu_f(d1*inv*g[lane+64]+be[lane+64]);
}
// att fill chunk ci (9 chunks of 1280 float4-per-b cover 11449)
DEVFN void fillc(float4* __restrict__ att4, long bbase, int ci, int tid){
  const int i0=ci*1280;
  const int iend = (i0+1280<11449)? i0+1280 : 11449;
#pragma unroll
  for (int r=0;r<4;r++){
    long base=(bbase+r)*11449L;
    for (int i=i0+tid; i<iend; i+=512){
      float v=(i>=1&&i<107)?(1.f/217088.f):(1.f/107.f);
      att4[base+i]=make_float4(v,v,v,v);
    }
  }
}

__global__ __launch_bounds__(512,2) void mega(
  const float* __restrict__ xn_enc_g, const float* __restrict__ Vv_g,
  const float* __restrict__ B1v_g, const float* __restrict__ sb1_g,
  const float* __restrict__ AU, const float* __restrict__ sa1,
  const float* __restrict__ Wcomb, const float* __restrict__ bcomb,
  const float* __restrict__ WvC, const float* __restrict__ bv2,
  const float* __restrict__ Wnv, const float* __restrict__ bnv,
  const float* __restrict__ lin_nw, const float* __restrict__ lin_nb,
  const float* __restrict__ lin_ng, const float* __restrict__ lin_nbeta,
  const float* __restrict__ lin_pg, const float* __restrict__ lin_pbeta,
  const float* __restrict__ ln_pg, const float* __restrict__ ln_pbeta,
  const float* __restrict__ out_nw, const float* __restrict__ out_nb,
  const float* __restrict__ out_pw, const float* __restrict__ out_pb,
  const float* __restrict__ skip_n, const float* __restrict__ skip_p,
  const float* __restrict__ ln_ng, const float* __restrict__ ln_nbeta,
  const float* __restrict__ cls_w, const float* __restrict__ cls_b,
  float* __restrict__ out)
{
  __shared__ float xe[512], x1[512], xA[512], W0s[512], Bv[512], Vvs[512];
  __shared__ float scratch[2048];     // us then Ys, per-b 512
  __shared__ float ss[2048];          // scores -> alpha, per-b [h][128]
  __shared__ float rowa[512], rowb[512];
  __shared__ float inv0[512], m1s[512], i1s[512];
  __shared__ float gAs[128], bAs[128], g0s[128], b0s[128];
  const int tid=threadIdx.x, lane=tid&63, wave=tid>>6, w2=wave>>1, half=wave&1;
  const int bbase=blockIdx.x*4, b=bbase+w2;
  const bool do_fill = (bbase>=24);
  float4* att4 = reinterpret_cast<float4*>(out + 4096);
  // stage
  xe[tid]=xn_enc_g[(long)bbase*128+tid];
  Bv[tid]=B1v_g[(long)bbase*128+tid];
  Vvs[tid]=Vv_g[(long)bbase*128+tid];
  if (tid<128){ gAs[tid]=lin_pg[tid]; bAs[tid]=lin_pbeta[tid]; g0s[tid]=ln_pg[tid]; b0s[tid]=ln_pbeta[tid]; }
  __syncthreads();
  dgemv128(lin_nw, lin_nb, xe, rowa, tid);                 // P1
  __syncthreads();
  if (half==0){                                            // P2: x1 = LN(rowa)+xe
    const float* rw=rowa+w2*128;
    float t0=rw[lane], t1=rw[lane+64];
    float m=wsum(t0+t1)*(1.f/128.f);
    float d0=t0-m,d1=t1-m;
    float var=wsum(d0*d0+d1*d1)*(1.f/128.f);
    float inv=rsqrtf(var+1e-5f);
    x1[w2*128+lane]   =d0*inv*lin_ng[lane]   +lin_nbeta[lane]   +xe[w2*128+lane];
    x1[w2*128+lane+64]=d1*inv*lin_ng[lane+64]+lin_nbeta[lane+64]+xe[w2*128+lane+64];
  } else if (do_fill) fillc(att4,bbase,0,tid);
  __syncthreads();
  dgemv512(Wcomb, bcomb, x1, scratch, tid);                // P3: us
  if (do_fill) fillc(att4,bbase,1,tid);
  __syncthreads();
  const float4* AU4=(const float4*)AU;
  const float2* BvW=(const float2*)(Bv+w2*128);
  const float2* VvW=(const float2*)(Vvs+w2*128);
  const float2* gAW=(const float2*)gAs;
  const float2* bAW=(const float2*)bAs;
  const float2* g0W=(const float2*)g0s;
  const float2* b0W=(const float2*)b0s;
  const float2* UsW=(const float2*)(scratch+w2*512);
  const float sb = sb1_g[b];
  const int p = half*64 + lane;
  const bool act = (p<106);
  // ===== P4: layer-0 fused dot+score sweep (lane = p) =====
  if (act){
    const float4* AUp = AU4 + p*64;
    float dt=0.f;
    float s10=0,s11=0,s12=0,s13=0, s20=0,s21=0,s22=0,s23=0;
#pragma unroll 2
    for (int c=0;c<64;c++){
      float4 au=AUp[c];
      float2 bb=BvW[c], vv=VvW[c], ga=gAW[c], ba=bAW[c];
      float2 q0=UsW[c], q1=UsW[64+c], q2=UsW[128+c], q3=UsW[192+c];
      dt += au.x*bb.x + au.y*bb.y;
      float px=(au.x+bb.x)*ga.x, py=(au.y+bb.y)*ga.y;
      float cx=ba.x+au.z+vv.x,   cy=ba.y+au.w+vv.y;
      s10+=px*q0.x+py*q0.y; s11+=px*q1.x+py*q1.y; s12+=px*q2.x+py*q2.y; s13+=px*q3.x+py*q3.y;
      s20+=cx*q0.x+cy*q0.y; s21+=cx*q1.x+cy*q1.y; s22+=cx*q2.x+cy*q2.y; s23+=cx*q3.x+cy*q3.y;
    }
    float iv = rsqrtf((sa1[p]+2.f*dt+sb)*(1.f/128.f)+1e-5f);
    inv0[w2*128+p]=iv;
    ss[w2*512+  0+p]=iv*s10+s20; ss[w2*512+128+p]=iv*s11+s21;
    ss[w2*512+256+p]=iv*s12+s22; ss[w2*512+384+p]=iv*s13+s23;
  }
  __syncthreads();
  // P5: softmax (16 jobs, 2/wave)
#pragma unroll
  for (int k=0;k<2;k++){
    int jj=wave*2+k, jb=jj>>2, jh=jj&3;
    float* row = ss + jb*512 + jh*128;
    float v1=(lane<106)? row[lane] : -1e30f;
    float v2=(lane+64<106)? row[lane+64] : -1e30f;
    float mx=wmaxr(fmaxf(v1,v2));
    float e1=(lane<106)? expf(v1-mx):0.f;
    float e2=(lane+64<106)? expf(v2-mx):0.f;
    float den=wsum(e1+e2);
    float rinv=1.f/den;
    if (lane<106) row[lane]=e1*rinv;
    if (lane+64<106) row[lane+64]=e2*rinv;
  }
  __syncthreads();
  // P6: layer-0 pass B (lane=c, p-range split across wave pair)
  float2 yb0,yb1,yb2,yb3;
  {
    const float2 bb=BvW[lane], vv=VvW[lane], ga=gAW[lane], ba=bAW[lane];
    float2 y0={0,0},y1={0,0},y2={0,0},y3={0,0};
    const float* al = ss + w2*512;
    const float* ivp = inv0 + w2*128;
    const int pst=half*53, pen=pst+53;
    for (int pp=pst; pp<pen; pp++){
      float4 au=AU4[pp*64+lane];
      float ivv=ivp[pp];
      float rx=(au.x+bb.x)*ivv*ga.x+ba.x+au.z+vv.x;
      float ry=(au.y+bb.y)*ivv*ga.y+ba.y+au.w+vv.y;
      float a0=al[pp],a1=al[128+pp],a2=al[256+pp],a3=al[384+pp];
      y0.x+=a0*rx; y0.y+=a0*ry; y1.x+=a1*rx; y1.y+=a1*ry;
      y2.x+=a2*rx; y2.y+=a2*ry; y3.x+=a3*rx; y3.y+=a3*ry;
    }
    yb0=y0; yb1=y1; yb2=y2; yb3=y3;
    if (half==0){
      float2* Yw=(float2*)(scratch+w2*512);
      Yw[lane]=y0; Yw[64+lane]=y1; Yw[128+lane]=y2; Yw[192+lane]=y3;
    }
  }
  __syncthreads();
  if (half==1){  // P6b: combine
    float2* Yw=(float2*)(scratch+w2*512);
    float2 t;
    t=Yw[lane];     t.x+=yb0.x; t.y+=yb0.y; Yw[lane]=t;
    t=Yw[64+lane];  t.x+=yb1.x; t.y+=yb1.y; Yw[64+lane]=t;
    t=Yw[128+lane]; t.x+=yb2.x; t.y+=yb2.y; Yw[128+lane]=t;
    t=Yw[192+lane]; t.x+=yb3.x; t.y+=yb3.y; Yw[192+lane]=t;
  } else if (do_fill) fillc(att4,bbase,2,tid);
  __syncthreads();
  daggv(WvC, bv2, scratch, rowa, tid);                     // P7
  __syncthreads();
  rowb[tid]=gelu_f(rowa[tid]);                             // P8
  if (do_fill) fillc(att4,bbase,3,tid);
  __syncthreads();
  dgemv128(out_nw, out_nb, rowb, rowa, tid);               // P9
  __syncthreads();
  if (half==0)                                             // P10
    rowmode2w(rowa+w2*128, x1+w2*128, xe+w2*128, ln_ng, ln_nbeta, skip_n[0], xA+w2*128, lane);
  else if (do_fill) fillc(att4,bbase,4,tid);
  __syncthreads();
  dgemv128(Wnv, bnv, x1, rowa, tid);                       // P11
  __syncthreads();
  rowb[tid]=gelu_f(rowa[tid]);                             // P12
  if (do_fill) fillc(att4,bbase,5,tid);
  __syncthreads();
  dgemv128(out_pw, out_pb, rowb, W0s, tid);                // P13
  __syncthreads();
  dgemv512(Wcomb+65536, bcomb+512, xA, scratch, tid);      // P14
  __syncthreads();
  // ===== P15: layer-1 stats + score sweeps (lane = p) =====
  const float sp0=sigm(skip_p[0]), omsp=1.f-sp0;
  const float2* W0W=(const float2*)(W0s+w2*128);
  if (act){
    const float4* AUp = AU4 + p*64;
    const float iv = inv0[w2*128+p];
    float st=0.f, sq=0.f;
#pragma unroll 2
    for (int c=0;c<64;c++){
      float4 au=AUp[c];
      float2 bb=BvW[c], vv=VvW[c], ga=gAW[c], ba=bAW[c], w0=W0W[c];
      float rx=(au.x+bb.x)*iv*ga.x+ba.x+au.z+vv.x;
      float ry=(au.y+bb.y)*iv*ga.y+ba.y+au.w+vv.y;
      float t0=sp0*w0.x+omsp*rx+au.z+vv.x;
      float t1=sp0*w0.y+omsp*ry+au.w+vv.y;
      st+=t0+t1; sq+=t0*t0+t1*t1;
    }
    float mA=st*(1.f/128.f);
    float ivA=rsqrtf(fmaxf(sq*(1.f/128.f)-mA*mA,0.f)+1e-5f);
    m1s[w2*128+p]=mA; i1s[w2*128+p]=ivA;
    float s0=0,s1=0,s2=0,s3=0;
#pragma unroll 2
    for (int c=0;c<64;c++){
      float4 au=AUp[c];
      float2 bb=BvW[c], vv=VvW[c], ga=gAW[c], ba=bAW[c], w0=W0W[c];
      float2 g0=g0W[c], b0v=b0W[c];
      float2 q0=UsW[c], q1=UsW[64+c], q2=UsW[128+c], q3=UsW[192+c];
      float rx=(au.x+bb.x)*iv*ga.x+ba.x+au.z+vv.x;
      float ry=(au.y+bb.y)*iv*ga.y+ba.y+au.w+vv.y;
      float t0=sp0*w0.x+omsp*rx+au.z+vv.x;
      float t1=sp0*w0.y+omsp*ry+au.w+vv.y;
      float r0=elu_f((t0-mA)*ivA*g0.x+b0v.x);
      float r1=elu_f((t1-mA)*ivA*g0.y+b0v.y);
      s0+=r0*q0.x+r1*q0.y; s1+=r0*q1.x+r1*q1.y;
      s2+=r0*q2.x+r1*q2.y; s3+=r0*q3.x+r1*q3.y;
    }
    ss[w2*512+  0+p]=s0; ss[w2*512+128+p]=s1;
    ss[w2*512+256+p]=s2; ss[w2*512+384+p]=s3;
  }
  __syncthreads();
  // P16: softmax
#pragma unroll
  for (int k=0;k<2;k++){
    int jj=wave*2+k, jb=jj>>2, jh=jj&3;
    float* row = ss + jb*512 + jh*128;
    float v1=(lane<106)? row[lane] : -1e30f;
    float v2=(lane+64<106)? row[lane+64] : -1e30f;
    float mx=wmaxr(fmaxf(v1,v2));
    float e1=(lane<106)? expf(v1-mx):0.f;
    float e2=(lane+64<106)? expf(v2-mx):0.f;
    float den=wsum(e1+e2);
    float rinv=1.f/den;
    if (lane<106) row[lane]=e1*rinv;
    if (lane+64<106) row[lane+64]=e2*rinv;
  }
  if (do_fill) fillc(att4,bbase,6,tid);
  __syncthreads();
  // P17: layer-1 pass B
  {
    const float2 bb=BvW[lane], vv=VvW[lane], ga=gAW[lane], ba=bAW[lane];
    const float2 w0=W0W[lane], g0=g0W[lane], b0v=b0W[lane];
    float2 y0={0,0},y1={0,0},y2={0,0},y3={0,0};
    const float* al = ss + w2*512;
    const float* ivp = inv0 + w2*128;
    const float* mp = m1s + w2*128;
    const float* ip = i1s + w2*128;
    const int pst=half*53, pen=pst+53;
    for (int pp=pst; pp<pen; pp++){
      float4 au=AU4[pp*64+lane];
      float ivv=ivp[pp], m=mp[pp], i2=ip[pp];
      float rx=(au.x+bb.x)*ivv*ga.x+ba.x+au.z+vv.x;
      float ry=(au.y+bb.y)*ivv*ga.y+ba.y+au.w+vv.y;
      float tx=sp0*w0.x+omsp*rx+au.z+vv.x;
      float ty=sp0*w0.y+omsp*ry+au.w+vv.y;
      float r0=elu_f((tx-m)*i2*g0.x+b0v.x);
      float r1=elu_f((ty-m)*i2*g0.y+b0v.y);
      float a0=al[pp],a1=al[128+pp],a2=al[256+pp],a3=al[384+pp];
      y0.x+=a0*r0; y0.y+=a0*r1; y1.x+=a1*r0; y1.y+=a1*r1;
      y2.x+=a2*r0; y2.y+=a2*r1; y3.x+=a3*r0; y3.y+=a3*r1;
    }
    yb0=y0; yb1=y1; yb2=y2; yb3=y3;
    if (half==0){
      float2* Yw=(float2*)(scratch+w2*512);
      Yw[lane]=y0; Yw[64+lane]=y1; Yw[128+lane]=y2; Yw[192+lane]=y3;
    }
  }
  __syncthreads();
  if (half==1){  // P17b
    float2* Yw=(float2*)(scratch+w2*512);
    float2 t;
    t=Yw[lane];     t.x+=yb0.x; t.y+=yb0.y; Yw[lane]=t;
    t=Yw[64+lane];  t.x+=yb1.x; t.y+=yb1.y; Yw[64+lane]=t;
    t=Yw[128+lane]; t.x+=yb2.x; t.y+=yb2.y; Yw[128+lane]=t;
    t=Yw[192+lane]; t.x+=yb3.x; t.y+=yb3.y; Yw[192+lane]=t;
  } else if (do_fill) fillc(att4,bbase,7,tid);
  __syncthreads();
  daggv(WvC+16384, bv2+128, scratch, rowa, tid);           // P18
  __syncthreads();
  rowb[tid]=gelu_f(rowa[tid]);                             // P19
  if (do_fill) fillc(att4,bbase,8,tid);
  __syncthreads();
  dgemv128(out_nw+16384, out_nb+128, rowb, rowa, tid);     // P20
  __syncthreads();
  if (half==0){                                            // P21
    rowmode2w(rowa+w2*128, xA+w2*128, xA+w2*128, ln_ng+128, ln_nbeta+128, skip_n[1], rowb+w2*128, lane);
    float xv0=rowb[w2*128+lane], xv1=rowb[w2*128+lane+64];
    float a0=xv0*cls_w[lane*2]  +xv1*cls_w[(lane+64)*2];
    float a1=xv0*cls_w[lane*2+1]+xv1*cls_w[(lane+64)*2+1];
    a0=wsum(a0); a1=wsum(a1);
    if (lane==0){ out[b*2]=a0+cls_b[0]; out[b*2+1]=a1+cls_b[1]; }
  }
}

__global__ __launch_bounds__(256) void prep(
  const float* __restrict__ news_emb,
  const float* __restrict__ ctx_w, const float* __restrict__ ctx_b,
  const float* __restrict__ enc_w, const float* __restrict__ enc_b,
  const float* __restrict__ enc_g, const float* __restrict__ enc_beta,
  const float* __restrict__ proj_w, const float* __restrict__ proj_b,
  const float* __restrict__ base_embs,
  const float* __restrict__ fus_w, const float* __restrict__ fus_b,
  const float* __restrict__ lin_pw, const float* __restrict__ lin_pb,
  const float* __restrict__ kqv_nw, const float* __restrict__ kqv_nb,
  const float* __restrict__ kqv_pw, const float* __restrict__ kqv_pb,
  const float* __restrict__ a_rel, const float* __restrict__ m_rel,
  const float* __restrict__ p_rel,
  float* __restrict__ Wcomb, float* __restrict__ bcomb,
  float* __restrict__ WvC, float* __restrict__ bv2,
  float* __restrict__ Wnv, float* __restrict__ bnv,
  float* __restrict__ AU, float* __restrict__ sa1,
  float* __restrict__ xn_enc, float* __restrict__ Vv,
  float* __restrict__ B1v, float* __restrict__ sb1)
{
  __shared__ __align__(16) float pool[6400];
  const int blk=blockIdx.x, tid=threadIdx.x, lane=tid&63, wid=tid>>6;
  if (blk < 135){
    float* sh  = pool;          // 2048
    float* row1= pool+2048;     // 128
    float* row2= pool+2176;     // 128
    float* row3= pool+2304;     // 128
    float* red = pool+2432;     // 256
    if (blk < 16){
      int l=blk>>3, jq=blk&7, h=jq>>1, cc0=(jq&1)*64;
      float* wk = sh;
      float ps = p_rel[(l*2+1)*4+h]*0.17677669529663687f;
      for (int idx=tid; idx<2048; idx+=256){
        int e=idx>>6, cl=idx&63;
        float acc=0.f;
#pragma unroll
        for (int d=0;d<32;d++)
          acc += kqv_pw[(long)l*49152 + (cc0+cl)*384 + h*32 + d]
               * a_rel[((l*2+1)*4+h)*1024 + d*32 + e];
        wk[e*64+cl]=acc*ps;
      }
      __syncthreads();
      for (int idx=tid; idx<8192; idx+=256){
        int c=idx>>6, jl=idx&63;
        float acc=0.f;
#pragma unroll
        for (int e=0;e<32;e++) acc += kqv_nw[(long)l*49152 + c*384 + 128 + h*32 + e]*wk[e*64+jl];
        Wcomb[(long)l*65536 + c*512 + h*128 + cc0 + jl]=acc;
      }
      if (tid<64){
        float acc=0.f;
#pragma unroll
        for (int e=0;e<32;e++) acc += kqv_nb[l*384 + 128 + h*32 + e]*wk[e*64+tid];
        bcomb[l*512 + h*128 + cc0 + tid]=acc;
      }
    } else if (blk < 24){
      int t=blk-16, l=t>>2, h=t&3;
      float* rl = sh;
      for (int i=tid;i<1024;i+=256) rl[i]=m_rel[((l*2+1)*4+h)*1024+i];
      __syncthreads();
      for (int idx=tid; idx<4096; idx+=256){
        int cc=idx>>5, d=idx&31;
        float acc=0.f;
#pragma unroll
        for (int dp=0;dp<32;dp++) acc += kqv_pw[(long)l*49152 + cc*384 + 256 + h*32 + dp]*rl[dp*32+d];
        WvC[l*16384 + (h*128+cc)*32 + d]=acc;
      }
    } else if (blk==24){
      {
        int l=tid>>7, j=tid&127, h=(j>>5)&3, d=j&31;
        float acc=0.f;
#pragma unroll
        for (int dp=0;dp<32;dp++) acc += kqv_pb[l*384+256+h*32+dp]*m_rel[((l*2+1)*4+h)*1024+dp*32+d];
        bv2[l*128+j]=acc;
      }
      if (tid < 128){
        int j=tid, h=j>>5, d=j&31;
        float acc=0.f;
#pragma unroll
        for (int dp=0;dp<32;dp++) acc += kqv_nb[256+h*32+dp]*m_rel[h*1024+dp*32+d];
        bnv[j]=acc;
      }
    } else if (blk < 29){
      int h=blk-25;
      float* rl=sh;
      for (int i=tid;i<1024;i+=256) rl[i]=m_rel[h*1024+i];
      __syncthreads();
      for (int idx=tid; idx<4096; idx+=256){
        int c=idx>>5, d=idx&31;
        float acc=0.f;
#pragma unroll
        for (int dp=0;dp<32;dp++) acc += kqv_nw[c*384+256+h*32+dp]*rl[dp*32+d];
        Wnv[c*128 + h*32 + d]=acc;
      }
    } else {
      // pred chain, one block per p -> AU + sa1
      int p = blk-29;
      float* xs1=sh;
      int j=tid&127, kg=tid>>7;
      for (int i=tid;i<1024;i+=256) xs1[i]=base_embs[(long)p*1024+i];
      __syncthreads();
      float acc=0.f;
#pragma unroll 4
      for (int k=0;k<512;k++) acc += xs1[kg*512+k]*proj_w[(long)(kg*512+k)*128+j];
      red[tid]=acc; __syncthreads();
      if (tid<128) row1[tid]=red[tid]+red[tid+128]+proj_b[tid];
      __syncthreads();
      acc=0.f;
#pragma unroll 4
      for (int i=0;i<64;i++) acc += row1[kg*64+i]*fus_w[(long)(kg*64+i)*128+j];
      red[tid]=acc; __syncthreads();
      if (tid<128) row2[tid]=red[tid]+red[tid+128]+fus_b[tid];
      __syncthreads();
      acc=0.f;
#pragma unroll 4
      for (int i=0;i<64;i++) acc += row2[kg*64+i]*lin_pw[(long)(kg*64+i)*128+j];
      red[tid]=acc; __syncthreads();
      if (tid<128) row3[tid]=red[tid]+red[tid+128];
      __syncthreads();
      if (wid==0){
        float t0=row3[lane], t1=row3[lane+64];
        float m=wsum(t0+t1)*(1.f/128.f);
        t0-=m; t1-=m;
        float ssq=wsum(t0*t0+t1*t1);
        row3[lane]=t0; row3[lane+64]=t1;
        if (lane==0) sa1[p]=ssq;
      }
      __syncthreads();
      if (tid<64){
        float4* AU4=(float4*)AU;
        AU4[p*64+tid]=make_float4(row3[2*tid],row3[2*tid+1],row2[2*tid],row2[2*tid+1]);
      }
    }
  } else {
    // ---- prep1: news pass, r0 = (blk-135)*4 ----
    float* xs   = pool;          // 4096
    float* redL = pool+4096;     // 1024
    float* rowsC= pool+5120;     // 512
    float* Vraw = pool+5632;     // 512
    float* bVbL = pool+6144;     // 128
    float* bB1L = pool+6272;     // 128
    const int r0=(blk-135)*4;
    const int j=tid&127, kg=tid>>7;
    for (int r=0;r<4;r++){
      float4 v=*(const float4*)(news_emb+(long)(r0+r)*1024+tid*4);
      *(float4*)(&xs[r*1024+tid*4])=v;
    }
    // local bVb = ctx_b@fusW2 ; bB1 = bVb@lin_pw + lin_pb
    {
      float acc=0.f;
#pragma unroll 4
      for (int i=0;i<64;i++) acc += ctx_b[kg*64+i]*fus_w[(128+kg*64+i)*128+j];
      redL[tid]=acc; __syncthreads();
      if (tid<128) bVbL[tid]=redL[tid]+redL[128+tid];
      __syncthreads();
      acc=0.f;
#pragma unroll 4
      for (int i=0;i<64;i++) acc += bVbL[kg*64+i]*lin_pw[(kg*64+i)*128+j];
      redL[tid]=acc; __syncthreads();
      if (tid<128) bB1L[tid]=redL[tid]+redL[128+tid]+lin_pb[tid];
      __syncthreads();
    }
    float ae0=0,ae1=0,ae2=0,ae3=0, ac0=0,ac1=0,ac2=0,ac3=0;
    {
      const float* We=enc_w+(long)(kg*512)*128+j;
      const float* Wc=ctx_w+(long)(kg*512)*128+j;
#pragma unroll 2
      for (int k=0;k<512;k++){
        float we=We[(long)k*128], wc=Wc[(long)k*128];
        float v0=xs[kg*512+k], v1=xs[1024+kg*512+k], v2=xs[2048+kg*512+k], v3=xs[3072+kg*512+k];
        ae0+=v0*we; ae1+=v1*we; ae2+=v2*we; ae3+=v3*we;
        ac0+=v0*wc; ac1+=v1*wc; ac2+=v2*wc; ac3+=v3*wc;
      }
    }
    redL[tid]=ae0; redL[256+tid]=ae1; redL[512+tid]=ae2; redL[768+tid]=ae3;
    __syncthreads();
    {
      float t0=redL[wid*256+lane]+redL[wid*256+128+lane]+enc_b[lane];
      float t1=redL[wid*256+lane+64]+redL[wid*256+128+lane+64]+enc_b[lane+64];
      float m=wsum(t0+t1)*(1.f/128.f);
      float d0=t0-m,d1=t1-m;
      float var=wsum(d0*d0+d1*d1)*(1.f/128.f);
      float inv=rsqrtf(var+1e-5f);
      xn_enc[(long)(r0+wid)*128+lane]   =elu_f(d0*inv*enc_g[lane]   +enc_beta[lane]);
      xn_enc[(long)(r0+wid)*128+lane+64]=elu_f(d1*inv*enc_g[lane+64]+enc_beta[lane+64]);
    }
    __syncthreads();
    redL[tid]=ac0; redL[256+tid]=ac1; redL[512+tid]=ac2; redL[768+tid]=ac3;
    __syncthreads();
    for (int i=tid;i<512;i+=256){
      int r=i>>7,jj=i&127;
      rowsC[r*128+jj]=redL[r*256+jj]+redL[r*256+128+jj];
    }
    __syncthreads();
    {
      const float* Wf=fus_w+(128+kg*64)*128+j;
      float a0=0,a1=0,a2=0,a3=0;
#pragma unroll 4
      for (int i=0;i<64;i++){
        float wv=Wf[i*128];
        a0+=rowsC[kg*64+i]*wv; a1+=rowsC[128+kg*64+i]*wv;
        a2+=rowsC[256+kg*64+i]*wv; a3+=rowsC[384+kg*64+i]*wv;
      }
      redL[tid]=a0; redL[256+tid]=a1; redL[512+tid]=a2; redL[768+tid]=a3;
    }
    __syncthreads();
    for (int i=tid;i<512;i+=256){
      int r=i>>7,jj=i&127;
      float v=redL[r*256+jj]+redL[r*256+128+jj];
      Vraw[r*128+jj]=v;
      Vv[(long)(r0+r)*128+jj]=v+bVbL[jj];
    }
    __syncthreads();
    {
      const float* Wl=lin_pw+(kg*64)*128+j;
      float a0=0,a1=0,a2=0,a3=0;
#pragma unroll 4
      for (int i=0;i<64;i++){
        float wv=Wl[i*128];
        a0+=Vraw[kg*64+i]*wv; a1+=Vraw[128+kg*64+i]*wv;
        a2+=Vraw[256+kg*64+i]*wv; a3+=Vraw[384+kg*64+i]*wv;
      }
      redL[tid]=a0; redL[256+tid]=a1; redL[512+tid]=a2; redL[768+tid]=a3;
    }
    __syncthreads();
    {
      float t0=redL[wid*256+lane]+redL[wid*256+128+lane]+bB1L[lane];
      float t1=redL[wid*256+lane+64]+redL[wid*256+128+lane+64]+bB1L[lane+64];
      float m=wsum(t0+t1)*(1.f/128.f);
      t0-=m; t1-=m;
      float ssq=wsum(t0*t0+t1*t1);
      B1v[(long)(r0+wid)*128+lane]=t0;
      B1v[(long)(r0+wid)*128+lane+64]=t1;
      if (lane==0) sb1[r0+wid]=ssq;
    }
  }
}

// head-fill: att for b < 24 (scratch zone), after mega
__global__ __launch_bounds__(256) void fill_att2(float4* __restrict__ att4){
  const float v1 = 1.f/107.f, v2 = 1.f/217088.f;
  long base = (long)blockIdx.x*11449;
  for (int i=threadIdx.x; i<11449; i+=256){
    float v = (i>=1 && i<107) ? v2 : v1;
    att4[base+i] = make_float4(v,v,v,v);
  }
}

extern "C" void kernel_launch(void* const* d_in, const int* in_sizes, int n_in,
                              void* d_out, int out_size, void* d_ws, size_t ws_size,
                              hipStream_t stream) {
  const float* news_emb = (const float*)d_in[0];
  const float* base_embs= (const float*)d_in[1];
  const float* ctx_w  = (const float*)d_in[2];
  const float* ctx_b  = (const float*)d_in[3];
  const float* proj_w = (const float*)d_in[4];
  const float* proj_b = (const float*)d_in[5];
  const float* fus_w  = (const float*)d_in[6];
  const float* fus_b  = (const float*)d_in[7];
  const float* enc_w  = (const float*)d_in[8];
  const float* enc_b  = (const float*)d_in[9];
  const float* enc_g  = (const float*)d_in[10];
  const float* enc_beta=(const float*)d_in[11];
  const float* lin_nw = (const float*)d_in[12];
  const float* lin_nb = (const float*)d_in[13];
  const float* lin_ng = (const float*)d_in[14];
  const float* lin_nbeta=(const float*)d_in[15];
  const float* kqv_nw = (const float*)d_in[16];
  const float* kqv_nb = (const float*)d_in[17];
  const float* out_nw = (const float*)d_in[18];
  const float* out_nb = (const float*)d_in[19];
  const float* skip_n = (const float*)d_in[20];
  const float* ln_ng  = (const float*)d_in[21];
  const float* ln_nbeta=(const float*)d_in[22];
  const float* lin_pw = (const float*)d_in[23];
  const float* lin_pb = (const float*)d_in[24];
  const float* lin_pg = (const float*)d_in[25];
  const float* lin_pbeta=(const float*)d_in[26];
  const float* kqv_pw = (const float*)d_in[27];
  const float* kqv_pb = (const float*)d_in[28];
  const float* out_pw = (const float*)d_in[29];
  const float* out_pb = (const float*)d_in[30];
  const float* skip_p = (const float*)d_in[31];
  const float* ln_pg  = (const float*)d_in[32];
  const float* ln_pbeta=(const float*)d_in[33];
  const float* a_rel  = (const float*)d_in[34];
  const float* m_rel  = (const float*)d_in[35];
  const float* p_rel  = (const float*)d_in[36];
  const float* cls_w  = (const float*)d_in[37];
  const float* cls_b  = (const float*)d_in[38];
  (void)in_sizes; (void)n_in; (void)out_size; (void)d_ws; (void)ws_size;

  float* out = (float*)d_out;
  float* S = out + 4096;            // att region as scratch (b<24 zone); head-filled last
  float* xn_enc = S + 0;            // 2048*128
  float* Vv     = S + 262144;       // 2048*128
  float* B1v    = S + 524288;       // 2048*128
  float* sb1    = S + 786432;       // 2048
  float* sa1    = S + 788480;       // 128
  float* AU     = S + 788608;       // 106*64*4 = 27136
  float* WvC    = S + 815744;       // 2*512*32
  float* bv2    = S + 848512;       // 2*128
  float* Wnv    = S + 848768;       // 128*128
  float* bnv    = S + 865152;       // 128
  float* Wcomb  = S + 865280;       // 2*128*512
  float* bcomb  = S + 996352;       // 2*512

  dim3 blk(256), blkL(512);
  prep<<<647,blk,0,stream>>>(news_emb,ctx_w,ctx_b,enc_w,enc_b,enc_g,enc_beta,
      proj_w,proj_b,base_embs,fus_w,fus_b,lin_pw,lin_pb,
      kqv_nw,kqv_nb,kqv_pw,kqv_pb,a_rel,m_rel,p_rel,
      Wcomb,bcomb,WvC,bv2,Wnv,bnv,AU,sa1,xn_enc,Vv,B1v,sb1);
  mega<<<512,blkL,0,stream>>>(xn_enc,Vv,B1v,sb1,AU,sa1,Wcomb,bcomb,WvC,bv2,Wnv,bnv,
      lin_nw,lin_nb,lin_ng,lin_nbeta,lin_pg,lin_pbeta,ln_pg,ln_pbeta,
      out_nw,out_nb,out_pw,out_pb,skip_n,skip_p,ln_ng,ln_nbeta,cls_w,cls_b,out);
  fill_att2<<<24,blk,0,stream>>>(reinterpret_cast<float4*>(S));
}